// Round 2
// baseline (434.491 us; speedup 1.0000x reference)
//
#include <hip/hip_runtime.h>
#include <hip/hip_bf16.h>

typedef __bf16 bf16_t;
typedef __attribute__((ext_vector_type(8))) __bf16 bf16x8;
typedef __attribute__((ext_vector_type(4))) __bf16 bf16x4;
typedef __attribute__((ext_vector_type(4))) float f32x4;

static constexpr int Bn = 4, Tn = 4096, Cn = 1024, Hn = 16, CSn = 128, Dn = 64, NCn = 32;

#define DEVINL __device__ __forceinline__

DEVINL float wsum64(float v) {
  v += __shfl_xor(v, 32, 64);
  v += __shfl_xor(v, 16, 64);
  v += __shfl_xor(v, 8, 64);
  v += __shfl_xor(v, 4, 64);
  v += __shfl_xor(v, 2, 64);
  v += __shfl_xor(v, 1, 64);
  return v;
}

// ------------- transpose fp32 (rows x cols) -> bf16 (cols x rows) --------------
__global__ void k_transpose(const float* __restrict__ in, bf16_t* __restrict__ out,
                            int rows, int cols) {
  __shared__ float tile[64][65];
  int c0 = blockIdx.x * 64, r0 = blockIdx.y * 64;
  int tx = threadIdx.x & 63, ty = threadIdx.x >> 6;
#pragma unroll
  for (int i = ty; i < 64; i += 4)
    tile[i][tx] = in[(size_t)(r0 + i) * cols + c0 + tx];
  __syncthreads();
#pragma unroll
  for (int i = ty; i < 64; i += 4)
    out[(size_t)(c0 + i) * rows + r0 + tx] = (bf16_t)tile[tx][i];
}

// ---------------- fused dual GEMM: gm = sigmoid(x@gateW+bg) * (x@markW+bm) ------
// X: [BT x 1024] fp32 row-major. Wtm/Wtg: [1024 x 1024] bf16 = W^T (k-contig).
__global__ __launch_bounds__(256) void k_dualgemm_gm(
    const float* __restrict__ X, const bf16_t* __restrict__ Wtm,
    const bf16_t* __restrict__ Wtg, const float* __restrict__ bm,
    const float* __restrict__ bg, float* __restrict__ gm) {
  constexpr int K = Cn, N = Cn;
  __shared__ __align__(16) bf16_t As[128][72];
  __shared__ __align__(16) bf16_t Bm[128][72];
  __shared__ __align__(16) bf16_t Bg[128][72];
  int tid = threadIdx.x;
  int m0 = blockIdx.y * 128, n0 = blockIdx.x * 128;
  int wave = tid >> 6, lane = tid & 63;
  int wm = wave >> 1, wn = wave & 1;
  int lr = lane & 15, lk = lane >> 4;
  f32x4 accP[4][4] = {};
  f32x4 accG[4][4] = {};
  for (int kt = 0; kt < K / 64; ++kt) {
    // A tile: fp32 -> bf16 inline (128 rows x 64 cols)
#pragma unroll
    for (int i = 0; i < 8; ++i) {
      int idx = tid + 256 * i;
      int row = idx >> 4, c4 = (idx & 15) * 4;
      float4 v = *reinterpret_cast<const float4*>(X + (size_t)(m0 + row) * K + kt * 64 + c4);
      bf16x4 o = {(bf16_t)v.x, (bf16_t)v.y, (bf16_t)v.z, (bf16_t)v.w};
      *reinterpret_cast<bf16x4*>(&As[row][c4]) = o;
    }
#pragma unroll
    for (int i = 0; i < 4; ++i) {
      int idx = tid + 256 * i;
      int row = idx >> 3, c8 = (idx & 7) * 8;
      *reinterpret_cast<uint4*>(&Bm[row][c8]) =
          *reinterpret_cast<const uint4*>(Wtm + (size_t)(n0 + row) * K + kt * 64 + c8);
      *reinterpret_cast<uint4*>(&Bg[row][c8]) =
          *reinterpret_cast<const uint4*>(Wtg + (size_t)(n0 + row) * K + kt * 64 + c8);
    }
    __syncthreads();
#pragma unroll
    for (int ks = 0; ks < 2; ++ks) {
      bf16x8 af[4], bmf[4], bgf[4];
#pragma unroll
      for (int i = 0; i < 4; ++i)
        af[i] = *reinterpret_cast<const bf16x8*>(&As[wm * 64 + i * 16 + lr][ks * 32 + lk * 8]);
#pragma unroll
      for (int j = 0; j < 4; ++j) {
        bmf[j] = *reinterpret_cast<const bf16x8*>(&Bm[wn * 64 + j * 16 + lr][ks * 32 + lk * 8]);
        bgf[j] = *reinterpret_cast<const bf16x8*>(&Bg[wn * 64 + j * 16 + lr][ks * 32 + lk * 8]);
      }
#pragma unroll
      for (int i = 0; i < 4; ++i)
#pragma unroll
        for (int j = 0; j < 4; ++j) {
          accP[i][j] = __builtin_amdgcn_mfma_f32_16x16x32_bf16(af[i], bmf[j], accP[i][j], 0, 0, 0);
          accG[i][j] = __builtin_amdgcn_mfma_f32_16x16x32_bf16(af[i], bgf[j], accG[i][j], 0, 0, 0);
        }
    }
    __syncthreads();
  }
#pragma unroll
  for (int j = 0; j < 4; ++j) {
    int col = n0 + wn * 64 + j * 16 + lr;
    float bmv = bm[col], bgv = bg[col];
#pragma unroll
    for (int i = 0; i < 4; ++i) {
      int rbase = m0 + wm * 64 + i * 16 + lk * 4;
#pragma unroll
      for (int r = 0; r < 4; ++r) {
        float p = accP[i][j][r] + bmv;
        float g = accG[i][j][r] + bgv;
        float s = 1.f / (1.f + __expf(-g));
        gm[(size_t)(rbase + r) * N + col] = s * p;
      }
    }
  }
}

// ---------------- per-(b,h,chunk) cumsum over pos (in-place) + chunk sums -------
__global__ __launch_bounds__(256) void k_chunk_cumsum(float* __restrict__ gm,
                                                      float* __restrict__ csum) {
  int gid = blockIdx.x * 4 + (threadIdx.x >> 6);  // (b*H+h)*NC + ci
  int lane = threadIdx.x & 63;
  int ci = gid & 31, bh = gid >> 5;
  int h = bh & 15, b = bh >> 4;
  size_t base = ((size_t)(b * Tn + ci * CSn)) * Cn + h * Dn + lane;
  float run = 0.f;
#pragma unroll 8
  for (int pos = 0; pos < CSn; ++pos) {
    run += gm[base + (size_t)pos * Cn];
    gm[base + (size_t)pos * Cn] = run;
  }
  csum[(size_t)gid * 64 + lane] = run;
}

// ---------------- exclusive carry cumsum over chunks + LN(D) --------------------
__global__ __launch_bounds__(64) void k_carry_ln(const float* __restrict__ csum,
                                                 float* __restrict__ ncar,
                                                 const float* __restrict__ g,
                                                 const float* __restrict__ be) {
  int bh = blockIdx.x;
  int d = threadIdx.x;
  float gd = g[d], bd = be[d];
  float run = 0.f;
  for (int ci = 0; ci < NCn; ++ci) {
    float v = run;  // exclusive prefix
    run += csum[((size_t)bh * NCn + ci) * 64 + d];
    float m = wsum64(v) * (1.f / 64.f);
    float dv = v - m;
    float var = wsum64(dv * dv) * (1.f / 64.f);
    ncar[((size_t)bh * NCn + ci) * 64 + d] = dv * rsqrtf(var + 1e-5f) * gd + bd;
  }
}

// ---------------- cards = LN(shifted lcm + nrm_carry), bf16 out -----------------
__global__ __launch_bounds__(256) void k_cards_ln(const float* __restrict__ lcm,
                                                  const float* __restrict__ ncar,
                                                  const float* __restrict__ g,
                                                  const float* __restrict__ be,
                                                  bf16_t* __restrict__ cards) {
  int row = blockIdx.x * 4 + (threadIdx.x >> 6);  // ((bh*NC)+ci)*CS + pos
  int d = threadIdx.x & 63;
  int pos = row & 127, rem = row >> 7;
  int ci = rem & 31, bh = rem >> 5;
  int h = bh & 15, b = bh >> 4;
  float v = ncar[((size_t)bh * NCn + ci) * 64 + d];
  if (pos > 0)
    v += lcm[((size_t)(b * Tn + ci * CSn + pos - 1)) * Cn + h * Dn + d];
  float m = wsum64(v) * (1.f / 64.f);
  float dv = v - m;
  float var = wsum64(dv * dv) * (1.f / 64.f);
  cards[(size_t)row * 64 + d] = (bf16_t)(dv * rsqrtf(var + 1e-5f) * g[d] + be[d]);
}

// ---------------- fused ho1 -> gelu -> ho2 per (b,h,chunk) ---------------------
// W1t: [128 x 128] bf16 = ho1_W^T ; W2t: [64 x 128] bf16 = ho2_W^T
__global__ __launch_bounds__(256) void k_ho_fused(
    const float* __restrict__ X, const bf16_t* __restrict__ cards,
    const bf16_t* __restrict__ W1t, const float* __restrict__ b1,
    const bf16_t* __restrict__ W2t, const float* __restrict__ b2,
    bf16_t* __restrict__ ho) {
  __shared__ __align__(16) bf16_t Cs[128][136];  // comb tile; reused as h tile
  __shared__ __align__(16) bf16_t Ws[128][136];  // W1t; rows 0..63 reused for W2t
  int tid = threadIdx.x;
  int ci = blockIdx.x & 31, bh = blockIdx.x >> 5;
  int h = bh & 15, b = bh >> 4;
  int wave = tid >> 6, lane = tid & 63;
  int wm = wave >> 1, wn = wave & 1;
  int lr = lane & 15, lk = lane >> 4;
  size_t xrow0 = (size_t)(b * Tn + ci * CSn);
  // x half: 128 rows x 64 cols fp32 -> bf16
#pragma unroll
  for (int i = 0; i < 8; ++i) {
    int idx = tid + 256 * i;
    int row = idx >> 4, c4 = (idx & 15) * 4;
    float4 v = *reinterpret_cast<const float4*>(X + (xrow0 + row) * Cn + h * Dn + c4);
    bf16x4 o = {(bf16_t)v.x, (bf16_t)v.y, (bf16_t)v.z, (bf16_t)v.w};
    *reinterpret_cast<bf16x4*>(&Cs[row][c4]) = o;
  }
  // cards half: 128 rows x 64 cols bf16
#pragma unroll
  for (int i = 0; i < 4; ++i) {
    int idx = tid + 256 * i;
    int row = idx >> 3, c8 = (idx & 7) * 8;
    *reinterpret_cast<uint4*>(&Cs[row][64 + c8]) =
        *reinterpret_cast<const uint4*>(cards + (((size_t)bh * NCn + ci) * CSn + row) * 64 + c8);
  }
  // W1t: 128 x 128 bf16
#pragma unroll
  for (int i = 0; i < 8; ++i) {
    int idx = tid + 256 * i;
    int row = idx >> 4, c8 = (idx & 15) * 8;
    *reinterpret_cast<uint4*>(&Ws[row][c8]) =
        *reinterpret_cast<const uint4*>(W1t + (size_t)row * 128 + c8);
  }
  __syncthreads();
  f32x4 acc[4][4] = {};
#pragma unroll
  for (int ks = 0; ks < 4; ++ks) {
    bf16x8 af[4], bfr[4];
#pragma unroll
    for (int i = 0; i < 4; ++i)
      af[i] = *reinterpret_cast<const bf16x8*>(&Cs[wm * 64 + i * 16 + lr][ks * 32 + lk * 8]);
#pragma unroll
    for (int j = 0; j < 4; ++j)
      bfr[j] = *reinterpret_cast<const bf16x8*>(&Ws[wn * 64 + j * 16 + lr][ks * 32 + lk * 8]);
#pragma unroll
    for (int i = 0; i < 4; ++i)
#pragma unroll
      for (int j = 0; j < 4; ++j)
        acc[i][j] = __builtin_amdgcn_mfma_f32_16x16x32_bf16(af[i], bfr[j], acc[i][j], 0, 0, 0);
  }
  __syncthreads();
  // h = gelu(acc + b1) into Cs; stage W2t into Ws rows 0..63
#pragma unroll
  for (int j = 0; j < 4; ++j) {
    int col = wn * 64 + j * 16 + lr;
    float bv = b1[col];
#pragma unroll
    for (int i = 0; i < 4; ++i) {
      int rbase = wm * 64 + i * 16 + lk * 4;
#pragma unroll
      for (int r = 0; r < 4; ++r) {
        float v = acc[i][j][r] + bv;
        float ge = 0.5f * v * (1.f + erff(v * 0.70710678f));
        Cs[rbase + r][col] = (bf16_t)ge;
      }
    }
  }
#pragma unroll
  for (int i = 0; i < 4; ++i) {
    int idx = tid + 256 * i;  // 64 rows x 16 oct-chunks
    int row = idx >> 4, c8 = (idx & 15) * 8;
    *reinterpret_cast<uint4*>(&Ws[row][c8]) =
        *reinterpret_cast<const uint4*>(W2t + (size_t)row * 128 + c8);
  }
  __syncthreads();
  f32x4 acc2[2][4] = {};
#pragma unroll
  for (int ks = 0; ks < 4; ++ks) {
    bf16x8 af[2], bfr[4];
#pragma unroll
    for (int i = 0; i < 2; ++i)
      af[i] = *reinterpret_cast<const bf16x8*>(&Cs[wave * 32 + i * 16 + lr][ks * 32 + lk * 8]);
#pragma unroll
    for (int j = 0; j < 4; ++j)
      bfr[j] = *reinterpret_cast<const bf16x8*>(&Ws[j * 16 + lr][ks * 32 + lk * 8]);
#pragma unroll
    for (int i = 0; i < 2; ++i)
#pragma unroll
      for (int j = 0; j < 4; ++j)
        acc2[i][j] = __builtin_amdgcn_mfma_f32_16x16x32_bf16(af[i], bfr[j], acc2[i][j], 0, 0, 0);
  }
#pragma unroll
  for (int j = 0; j < 4; ++j) {
    int dd = j * 16 + lr;
    float bv = b2[dd];
#pragma unroll
    for (int i = 0; i < 2; ++i) {
      int pbase = wave * 32 + i * 16 + lk * 4;
#pragma unroll
      for (int r = 0; r < 4; ++r)
        ho[(xrow0 + pbase + r) * Cn + h * Dn + dd] = (bf16_t)(acc2[i][j][r] + bv);
    }
  }
}

// ---------------- proj GEMM: out = A @ Wt^T + bias (fp32 out) ------------------
__global__ __launch_bounds__(256) void k_gemm_bt(
    const bf16_t* __restrict__ A, const bf16_t* __restrict__ Wt,
    const float* __restrict__ bias, float* __restrict__ out) {
  constexpr int K = Cn, N = Cn;
  __shared__ __align__(16) bf16_t As[128][72];
  __shared__ __align__(16) bf16_t Bs[128][72];
  int tid = threadIdx.x;
  int m0 = blockIdx.y * 128, n0 = blockIdx.x * 128;
  int wave = tid >> 6, lane = tid & 63;
  int wm = wave >> 1, wn = wave & 1;
  int lr = lane & 15, lk = lane >> 4;
  f32x4 acc[4][4] = {};
  for (int kt = 0; kt < K / 64; ++kt) {
#pragma unroll
    for (int i = 0; i < 4; ++i) {
      int idx = tid + 256 * i;
      int row = idx >> 3, c8 = (idx & 7) * 8;
      *reinterpret_cast<uint4*>(&As[row][c8]) =
          *reinterpret_cast<const uint4*>(A + (size_t)(m0 + row) * K + kt * 64 + c8);
      *reinterpret_cast<uint4*>(&Bs[row][c8]) =
          *reinterpret_cast<const uint4*>(Wt + (size_t)(n0 + row) * K + kt * 64 + c8);
    }
    __syncthreads();
#pragma unroll
    for (int ks = 0; ks < 2; ++ks) {
      bf16x8 af[4], bfr[4];
#pragma unroll
      for (int i = 0; i < 4; ++i)
        af[i] = *reinterpret_cast<const bf16x8*>(&As[wm * 64 + i * 16 + lr][ks * 32 + lk * 8]);
#pragma unroll
      for (int j = 0; j < 4; ++j)
        bfr[j] = *reinterpret_cast<const bf16x8*>(&Bs[wn * 64 + j * 16 + lr][ks * 32 + lk * 8]);
#pragma unroll
      for (int i = 0; i < 4; ++i)
#pragma unroll
        for (int j = 0; j < 4; ++j)
          acc[i][j] = __builtin_amdgcn_mfma_f32_16x16x32_bf16(af[i], bfr[j], acc[i][j], 0, 0, 0);
    }
    __syncthreads();
  }
#pragma unroll
  for (int j = 0; j < 4; ++j) {
    int col = n0 + wn * 64 + j * 16 + lr;
    float bv = bias[col];
#pragma unroll
    for (int i = 0; i < 4; ++i) {
      int rbase = m0 + wm * 64 + i * 16 + lk * 4;
#pragma unroll
      for (int r = 0; r < 4; ++r)
        out[(size_t)(rbase + r) * N + col] = acc[i][j][r] + bv;
    }
  }
}

// ---------------- final LN over C + residual (all fp32) -------------------------
__global__ __launch_bounds__(256) void k_ln_residual(
    const float* __restrict__ pre, const float* __restrict__ X,
    const float* __restrict__ g, const float* __restrict__ be,
    float* __restrict__ out) {
  int row = blockIdx.x, t = threadIdx.x;
  size_t base = (size_t)row * Cn + t * 4;
  float4 pv = *reinterpret_cast<const float4*>(pre + base);
  float s = pv.x + pv.y + pv.z + pv.w;
  float q = pv.x * pv.x + pv.y * pv.y + pv.z * pv.z + pv.w * pv.w;
  s = wsum64(s);
  q = wsum64(q);
  __shared__ float red[8];
  int wv = t >> 6, ln = t & 63;
  if (ln == 0) { red[wv] = s; red[4 + wv] = q; }
  __syncthreads();
  float tot = red[0] + red[1] + red[2] + red[3];
  float totq = red[4] + red[5] + red[6] + red[7];
  float mean = tot * (1.f / 1024.f);
  float var = totq * (1.f / 1024.f) - mean * mean;
  float rs = rsqrtf(fmaxf(var, 0.f) + 1e-5f);
  float4 xv = *reinterpret_cast<const float4*>(X + base);
  float4 gv = *reinterpret_cast<const float4*>(g + t * 4);
  float4 bv = *reinterpret_cast<const float4*>(be + t * 4);
  float4 o;
  o.x = (pv.x - mean) * rs * gv.x + bv.x + xv.x;
  o.y = (pv.y - mean) * rs * gv.y + bv.y + xv.y;
  o.z = (pv.z - mean) * rs * gv.z + bv.z + xv.z;
  o.w = (pv.w - mean) * rs * gv.w + bv.w + xv.w;
  *reinterpret_cast<float4*>(out + base) = o;
}

extern "C" void kernel_launch(void* const* d_in, const int* in_sizes, int n_in,
                              void* d_out, int out_size, void* d_ws, size_t ws_size,
                              hipStream_t stream) {
  const float* x       = (const float*)d_in[0];
  const float* mark_W  = (const float*)d_in[1];
  const float* mark_b  = (const float*)d_in[2];
  const float* gate_W  = (const float*)d_in[3];
  const float* gate_b  = (const float*)d_in[4];
  const float* carry_g = (const float*)d_in[5];
  const float* carry_b = (const float*)d_in[6];
  const float* card_g  = (const float*)d_in[7];
  const float* card_b  = (const float*)d_in[8];
  const float* ho1_W   = (const float*)d_in[9];
  const float* ho1_b   = (const float*)d_in[10];
  const float* ho2_W   = (const float*)d_in[11];
  const float* ho2_b   = (const float*)d_in[12];
  const float* proj_W  = (const float*)d_in[13];
  const float* proj_b  = (const float*)d_in[14];
  const float* ln_g    = (const float*)d_in[15];
  const float* ln_b    = (const float*)d_in[16];
  float* out = (float*)d_out;

  char* ws = (char*)d_ws;
  // region0: gm fp32 (67.1MB), later reused for outpre fp32
  float*  gm     = (float*)(ws + 0);
  float*  outpre = (float*)(ws + 0);
  bf16_t* cards  = (bf16_t*)(ws + 67108864);
  bf16_t* hobuf  = (bf16_t*)(ws + 100663296);
  float*  csum   = (float*)(ws + 134217728);
  float*  ncar   = (float*)(ws + 134742016);
  bf16_t* wtm    = (bf16_t*)(ws + 135266304);
  bf16_t* wtg    = (bf16_t*)(ws + 137363456);
  bf16_t* wtp    = (bf16_t*)(ws + 139460608);
  bf16_t* wt1    = (bf16_t*)(ws + 141557760);
  bf16_t* wt2    = (bf16_t*)(ws + 141590528);

  k_transpose<<<dim3(16, 16), 256, 0, stream>>>(mark_W, wtm, 1024, 1024);
  k_transpose<<<dim3(16, 16), 256, 0, stream>>>(gate_W, wtg, 1024, 1024);
  k_transpose<<<dim3(16, 16), 256, 0, stream>>>(proj_W, wtp, 1024, 1024);
  k_transpose<<<dim3(2, 2),   256, 0, stream>>>(ho1_W, wt1, 128, 128);
  k_transpose<<<dim3(1, 2),   256, 0, stream>>>(ho2_W, wt2, 128, 64);

  k_dualgemm_gm<<<dim3(8, 128), 256, 0, stream>>>(x, wtm, wtg, mark_b, gate_b, gm);
  k_chunk_cumsum<<<512, 256, 0, stream>>>(gm, csum);
  k_carry_ln<<<64, 64, 0, stream>>>(csum, ncar, carry_g, carry_b);
  k_cards_ln<<<65536, 256, 0, stream>>>(gm, ncar, card_g, card_b, cards);
  k_ho_fused<<<2048, 256, 0, stream>>>(x, cards, wt1, ho1_b, wt2, ho2_b, hobuf);
  k_gemm_bt<<<dim3(8, 128), 256, 0, stream>>>(hobuf, wtp, proj_b, outpre);
  k_ln_residual<<<16384, 256, 0, stream>>>(outpre, x, ln_g, ln_b, out);
}

// Round 3
// 323.961 us; speedup vs baseline: 1.3412x; 1.3412x over previous
//
#include <hip/hip_runtime.h>
#include <hip/hip_bf16.h>

typedef __bf16 bf16_t;
typedef __attribute__((ext_vector_type(8))) __bf16 bf16x8;
typedef __attribute__((ext_vector_type(4))) __bf16 bf16x4;
typedef __attribute__((ext_vector_type(4))) float f32x4;

static constexpr int Bn = 4, Tn = 4096, Cn = 1024, Hn = 16, CSn = 128, Dn = 64, NCn = 32;

#define DEVINL __device__ __forceinline__

DEVINL float wsum64(float v) {
  v += __shfl_xor(v, 32, 64);
  v += __shfl_xor(v, 16, 64);
  v += __shfl_xor(v, 8, 64);
  v += __shfl_xor(v, 4, 64);
  v += __shfl_xor(v, 2, 64);
  v += __shfl_xor(v, 1, 64);
  return v;
}

// direct global->LDS, 16B per lane; LDS dest is wave-uniform base + lane*16
DEVINL void gld16(const bf16_t* g, bf16_t* l) {
  __builtin_amdgcn_global_load_lds(
      (const __attribute__((address_space(1))) unsigned int*)(g),
      (__attribute__((address_space(3))) unsigned int*)(l), 16, 0, 0);
}

// ------------- x fp32 -> bf16 (contiguous) -------------------------------------
__global__ __launch_bounds__(256) void k_xbf(const float* __restrict__ in,
                                             bf16_t* __restrict__ out) {
  int i = blockIdx.x * 256 + threadIdx.x;  // one per 8 elements
  float4 a = *reinterpret_cast<const float4*>(in + (size_t)i * 8);
  float4 b = *reinterpret_cast<const float4*>(in + (size_t)i * 8 + 4);
  bf16x8 o = {(bf16_t)a.x, (bf16_t)a.y, (bf16_t)a.z, (bf16_t)a.w,
              (bf16_t)b.x, (bf16_t)b.y, (bf16_t)b.z, (bf16_t)b.w};
  *reinterpret_cast<bf16x8*>(out + (size_t)i * 8) = o;
}

// ------------- transpose fp32 (rows x cols) -> bf16 (cols x rows) --------------
__global__ void k_transpose(const float* __restrict__ in, bf16_t* __restrict__ out,
                            int rows, int cols) {
  __shared__ float tile[64][65];
  int c0 = blockIdx.x * 64, r0 = blockIdx.y * 64;
  int tx = threadIdx.x & 63, ty = threadIdx.x >> 6;
#pragma unroll
  for (int i = ty; i < 64; i += 4)
    tile[i][tx] = in[(size_t)(r0 + i) * cols + c0 + tx];
  __syncthreads();
#pragma unroll
  for (int i = ty; i < 64; i += 4)
    out[(size_t)(c0 + i) * rows + r0 + tx] = (bf16_t)tile[tx][i];
}

// ---------------- fused dual GEMM: gm = sigmoid(x@gateW+bg) * (x@markW+bm) ------
// X: [BT x 1024] bf16. Wtm/Wtg: [1024 x 1024] bf16 = W^T (k-contig). gm: bf16.
__global__ __launch_bounds__(256, 2) void k_dualgemm_gm(
    const bf16_t* __restrict__ X, const bf16_t* __restrict__ Wtm,
    const bf16_t* __restrict__ Wtg, const float* __restrict__ bm,
    const float* __restrict__ bg, bf16_t* __restrict__ gm) {
  constexpr int K = Cn, N = Cn;
  __shared__ __align__(16) bf16_t As[128 * 64];
  __shared__ __align__(16) bf16_t Bms[128 * 64];
  __shared__ __align__(16) bf16_t Bgs[128 * 64];
  int tid = threadIdx.x;
  int m0 = blockIdx.y * 128, n0 = blockIdx.x * 128;
  int wave = tid >> 6, lane = tid & 63;
  int wm = wave >> 1, wn = wave & 1;
  int lr = lane & 15, lk = lane >> 4;
  int srow = lane >> 3, scol = (lane & 7) * 8;  // within 8-row chunk
  f32x4 accP[4][4] = {};
  f32x4 accG[4][4] = {};
  for (int kt = 0; kt < K / 64; ++kt) {
#pragma unroll
    for (int c2 = 0; c2 < 4; ++c2) {
      int chunk = wave * 4 + c2;       // 0..15
      int row = chunk * 8 + srow;      // 0..127
      size_t goff = (size_t)row * K + kt * 64 + scol;
      gld16(X + (size_t)m0 * K + goff, As + chunk * 512);
      gld16(Wtm + (size_t)n0 * K + goff, Bms + chunk * 512);
      gld16(Wtg + (size_t)n0 * K + goff, Bgs + chunk * 512);
    }
    __syncthreads();
#pragma unroll
    for (int ks = 0; ks < 2; ++ks) {
      bf16x8 af[4], bmf[4], bgf[4];
#pragma unroll
      for (int i = 0; i < 4; ++i)
        af[i] = *reinterpret_cast<const bf16x8*>(&As[(wm * 64 + i * 16 + lr) * 64 + ks * 32 + lk * 8]);
#pragma unroll
      for (int j = 0; j < 4; ++j) {
        bmf[j] = *reinterpret_cast<const bf16x8*>(&Bms[(wn * 64 + j * 16 + lr) * 64 + ks * 32 + lk * 8]);
        bgf[j] = *reinterpret_cast<const bf16x8*>(&Bgs[(wn * 64 + j * 16 + lr) * 64 + ks * 32 + lk * 8]);
      }
#pragma unroll
      for (int i = 0; i < 4; ++i)
#pragma unroll
        for (int j = 0; j < 4; ++j) {
          accP[i][j] = __builtin_amdgcn_mfma_f32_16x16x32_bf16(af[i], bmf[j], accP[i][j], 0, 0, 0);
          accG[i][j] = __builtin_amdgcn_mfma_f32_16x16x32_bf16(af[i], bgf[j], accG[i][j], 0, 0, 0);
        }
    }
    __syncthreads();
  }
#pragma unroll
  for (int j = 0; j < 4; ++j) {
    int col = n0 + wn * 64 + j * 16 + lr;
    float bmv = bm[col], bgv = bg[col];
#pragma unroll
    for (int i = 0; i < 4; ++i) {
      int rbase = m0 + wm * 64 + i * 16 + lk * 4;
#pragma unroll
      for (int r = 0; r < 4; ++r) {
        float p = accP[i][j][r] + bmv;
        float g = accG[i][j][r] + bgv;
        float s = 1.f / (1.f + __expf(-g));
        gm[(size_t)(rbase + r) * N + col] = (bf16_t)(s * p);
      }
    }
  }
}

// ---------------- per-(b,h,chunk) cumsum over pos (in-place, bf16) --------------
__global__ __launch_bounds__(256) void k_chunk_cumsum(bf16_t* __restrict__ gm,
                                                      float* __restrict__ csum) {
  int gid = blockIdx.x * 4 + (threadIdx.x >> 6);  // (b*H+h)*NC + ci
  int lane = threadIdx.x & 63;
  int ci = gid & 31, bh = gid >> 5;
  int h = bh & 15, b = bh >> 4;
  size_t base = ((size_t)(b * Tn + ci * CSn)) * Cn + h * Dn + lane;
  float run = 0.f;
#pragma unroll 8
  for (int pos = 0; pos < CSn; ++pos) {
    run += (float)gm[base + (size_t)pos * Cn];
    gm[base + (size_t)pos * Cn] = (bf16_t)run;
  }
  csum[(size_t)gid * 64 + lane] = run;
}

// ---------------- exclusive carry cumsum over chunks + LN(D) --------------------
__global__ __launch_bounds__(64) void k_carry_ln(const float* __restrict__ csum,
                                                 float* __restrict__ ncar,
                                                 const float* __restrict__ g,
                                                 const float* __restrict__ be) {
  int bh = blockIdx.x;
  int d = threadIdx.x;
  float gd = g[d], bd = be[d];
  float run = 0.f;
  for (int ci = 0; ci < NCn; ++ci) {
    float v = run;  // exclusive prefix
    run += csum[((size_t)bh * NCn + ci) * 64 + d];
    float m = wsum64(v) * (1.f / 64.f);
    float dv = v - m;
    float var = wsum64(dv * dv) * (1.f / 64.f);
    ncar[((size_t)bh * NCn + ci) * 64 + d] = dv * rsqrtf(var + 1e-5f) * gd + bd;
  }
}

// ---------------- cards = LN(shifted lcm + nrm_carry), bf16 out -----------------
__global__ __launch_bounds__(256) void k_cards_ln(const bf16_t* __restrict__ lcm,
                                                  const float* __restrict__ ncar,
                                                  const float* __restrict__ g,
                                                  const float* __restrict__ be,
                                                  bf16_t* __restrict__ cards) {
  int row = blockIdx.x * 4 + (threadIdx.x >> 6);  // ((bh*NC)+ci)*CS + pos
  int d = threadIdx.x & 63;
  int pos = row & 127, rem = row >> 7;
  int ci = rem & 31, bh = rem >> 5;
  int h = bh & 15, b = bh >> 4;
  float v = ncar[((size_t)bh * NCn + ci) * 64 + d];
  if (pos > 0)
    v += (float)lcm[((size_t)(b * Tn + ci * CSn + pos - 1)) * Cn + h * Dn + d];
  float m = wsum64(v) * (1.f / 64.f);
  float dv = v - m;
  float var = wsum64(dv * dv) * (1.f / 64.f);
  cards[(size_t)row * 64 + d] = (bf16_t)(dv * rsqrtf(var + 1e-5f) * g[d] + be[d]);
}

// ---------------- fused ho1 -> gelu -> ho2 per (b,h,chunk) ---------------------
// W1t: [128 x 128] bf16 = ho1_W^T ; W2t: [64 x 128] bf16 = ho2_W^T
__global__ __launch_bounds__(256) void k_ho_fused(
    const bf16_t* __restrict__ X, const bf16_t* __restrict__ cards,
    const bf16_t* __restrict__ W1t, const float* __restrict__ b1,
    const bf16_t* __restrict__ W2t, const float* __restrict__ b2,
    bf16_t* __restrict__ ho) {
  __shared__ __align__(16) bf16_t Cs[128][136];  // comb tile; reused as h tile
  __shared__ __align__(16) bf16_t Ws[128][136];  // W1t; rows 0..63 reused for W2t
  int tid = threadIdx.x;
  int ci = blockIdx.x & 31, bh = blockIdx.x >> 5;
  int h = bh & 15, b = bh >> 4;
  int wave = tid >> 6, lane = tid & 63;
  int wm = wave >> 1, wn = wave & 1;
  int lr = lane & 15, lk = lane >> 4;
  size_t xrow0 = (size_t)(b * Tn + ci * CSn);
  // x half: 128 rows x 64 cols bf16
#pragma unroll
  for (int i = 0; i < 4; ++i) {
    int idx = tid + 256 * i;
    int row = idx >> 3, c8 = (idx & 7) * 8;
    *reinterpret_cast<uint4*>(&Cs[row][c8]) =
        *reinterpret_cast<const uint4*>(X + (xrow0 + row) * Cn + h * Dn + c8);
  }
  // cards half: 128 rows x 64 cols bf16
#pragma unroll
  for (int i = 0; i < 4; ++i) {
    int idx = tid + 256 * i;
    int row = idx >> 3, c8 = (idx & 7) * 8;
    *reinterpret_cast<uint4*>(&Cs[row][64 + c8]) =
        *reinterpret_cast<const uint4*>(cards + (((size_t)bh * NCn + ci) * CSn + row) * 64 + c8);
  }
  // W1t: 128 x 128 bf16
#pragma unroll
  for (int i = 0; i < 8; ++i) {
    int idx = tid + 256 * i;
    int row = idx >> 4, c8 = (idx & 15) * 8;
    *reinterpret_cast<uint4*>(&Ws[row][c8]) =
        *reinterpret_cast<const uint4*>(W1t + (size_t)row * 128 + c8);
  }
  __syncthreads();
  f32x4 acc[4][4] = {};
#pragma unroll
  for (int ks = 0; ks < 4; ++ks) {
    bf16x8 af[4], bfr[4];
#pragma unroll
    for (int i = 0; i < 4; ++i)
      af[i] = *reinterpret_cast<const bf16x8*>(&Cs[wm * 64 + i * 16 + lr][ks * 32 + lk * 8]);
#pragma unroll
    for (int j = 0; j < 4; ++j)
      bfr[j] = *reinterpret_cast<const bf16x8*>(&Ws[wn * 64 + j * 16 + lr][ks * 32 + lk * 8]);
#pragma unroll
    for (int i = 0; i < 4; ++i)
#pragma unroll
      for (int j = 0; j < 4; ++j)
        acc[i][j] = __builtin_amdgcn_mfma_f32_16x16x32_bf16(af[i], bfr[j], acc[i][j], 0, 0, 0);
  }
  __syncthreads();
  // h = gelu(acc + b1) into Cs; stage W2t into Ws rows 0..63
#pragma unroll
  for (int j = 0; j < 4; ++j) {
    int col = wn * 64 + j * 16 + lr;
    float bv = b1[col];
#pragma unroll
    for (int i = 0; i < 4; ++i) {
      int rbase = wm * 64 + i * 16 + lk * 4;
#pragma unroll
      for (int r = 0; r < 4; ++r) {
        float v = acc[i][j][r] + bv;
        float ge = 0.5f * v * (1.f + erff(v * 0.70710678f));
        Cs[rbase + r][col] = (bf16_t)ge;
      }
    }
  }
#pragma unroll
  for (int i = 0; i < 4; ++i) {
    int idx = tid + 256 * i;  // 64 rows x 16 oct-chunks
    int row = idx >> 4, c8 = (idx & 15) * 8;
    *reinterpret_cast<uint4*>(&Ws[row][c8]) =
        *reinterpret_cast<const uint4*>(W2t + (size_t)row * 128 + c8);
  }
  __syncthreads();
  f32x4 acc2[2][4] = {};
#pragma unroll
  for (int ks = 0; ks < 4; ++ks) {
    bf16x8 af[2], bfr[4];
#pragma unroll
    for (int i = 0; i < 2; ++i)
      af[i] = *reinterpret_cast<const bf16x8*>(&Cs[wave * 32 + i * 16 + lr][ks * 32 + lk * 8]);
#pragma unroll
    for (int j = 0; j < 4; ++j)
      bfr[j] = *reinterpret_cast<const bf16x8*>(&Ws[j * 16 + lr][ks * 32 + lk * 8]);
#pragma unroll
    for (int i = 0; i < 2; ++i)
#pragma unroll
      for (int j = 0; j < 4; ++j)
        acc2[i][j] = __builtin_amdgcn_mfma_f32_16x16x32_bf16(af[i], bfr[j], acc2[i][j], 0, 0, 0);
  }
#pragma unroll
  for (int j = 0; j < 4; ++j) {
    int dd = j * 16 + lr;
    float bv = b2[dd];
#pragma unroll
    for (int i = 0; i < 2; ++i) {
      int pbase = wave * 32 + i * 16 + lk * 4;
#pragma unroll
      for (int r = 0; r < 4; ++r)
        ho[(xrow0 + pbase + r) * Cn + h * Dn + dd] = (bf16_t)(acc2[i][j][r] + bv);
    }
  }
}

// ---------------- proj GEMM: out = A @ Wt^T + bias (fp32 out) ------------------
__global__ __launch_bounds__(256, 2) void k_gemm_bt(
    const bf16_t* __restrict__ A, const bf16_t* __restrict__ Wt,
    const float* __restrict__ bias, float* __restrict__ out) {
  constexpr int K = Cn, N = Cn;
  __shared__ __align__(16) bf16_t As[128 * 64];
  __shared__ __align__(16) bf16_t Bs[128 * 64];
  int tid = threadIdx.x;
  int m0 = blockIdx.y * 128, n0 = blockIdx.x * 128;
  int wave = tid >> 6, lane = tid & 63;
  int wm = wave >> 1, wn = wave & 1;
  int lr = lane & 15, lk = lane >> 4;
  int srow = lane >> 3, scol = (lane & 7) * 8;
  f32x4 acc[4][4] = {};
  for (int kt = 0; kt < K / 64; ++kt) {
#pragma unroll
    for (int c2 = 0; c2 < 4; ++c2) {
      int chunk = wave * 4 + c2;
      int row = chunk * 8 + srow;
      size_t goff = (size_t)row * K + kt * 64 + scol;
      gld16(A + (size_t)m0 * K + goff, As + chunk * 512);
      gld16(Wt + (size_t)n0 * K + goff, Bs + chunk * 512);
    }
    __syncthreads();
#pragma unroll
    for (int ks = 0; ks < 2; ++ks) {
      bf16x8 af[4], bfr[4];
#pragma unroll
      for (int i = 0; i < 4; ++i)
        af[i] = *reinterpret_cast<const bf16x8*>(&As[(wm * 64 + i * 16 + lr) * 64 + ks * 32 + lk * 8]);
#pragma unroll
      for (int j = 0; j < 4; ++j)
        bfr[j] = *reinterpret_cast<const bf16x8*>(&Bs[(wn * 64 + j * 16 + lr) * 64 + ks * 32 + lk * 8]);
#pragma unroll
      for (int i = 0; i < 4; ++i)
#pragma unroll
        for (int j = 0; j < 4; ++j)
          acc[i][j] = __builtin_amdgcn_mfma_f32_16x16x32_bf16(af[i], bfr[j], acc[i][j], 0, 0, 0);
    }
    __syncthreads();
  }
#pragma unroll
  for (int j = 0; j < 4; ++j) {
    int col = n0 + wn * 64 + j * 16 + lr;
    float bv = bias[col];
#pragma unroll
    for (int i = 0; i < 4; ++i) {
      int rbase = m0 + wm * 64 + i * 16 + lk * 4;
#pragma unroll
      for (int r = 0; r < 4; ++r)
        out[(size_t)(rbase + r) * N + col] = acc[i][j][r] + bv;
    }
  }
}

// ---------------- final LN over C + residual (all fp32) -------------------------
__global__ __launch_bounds__(256) void k_ln_residual(
    const float* __restrict__ pre, const float* __restrict__ X,
    const float* __restrict__ g, const float* __restrict__ be,
    float* __restrict__ out) {
  int row = blockIdx.x, t = threadIdx.x;
  size_t base = (size_t)row * Cn + t * 4;
  float4 pv = *reinterpret_cast<const float4*>(pre + base);
  float s = pv.x + pv.y + pv.z + pv.w;
  float q = pv.x * pv.x + pv.y * pv.y + pv.z * pv.z + pv.w * pv.w;
  s = wsum64(s);
  q = wsum64(q);
  __shared__ float red[8];
  int wv = t >> 6, ln = t & 63;
  if (ln == 0) { red[wv] = s; red[4 + wv] = q; }
  __syncthreads();
  float tot = red[0] + red[1] + red[2] + red[3];
  float totq = red[4] + red[5] + red[6] + red[7];
  float mean = tot * (1.f / 1024.f);
  float var = totq * (1.f / 1024.f) - mean * mean;
  float rs = rsqrtf(fmaxf(var, 0.f) + 1e-5f);
  float4 xv = *reinterpret_cast<const float4*>(X + base);
  float4 gv = *reinterpret_cast<const float4*>(g + t * 4);
  float4 bv = *reinterpret_cast<const float4*>(be + t * 4);
  float4 o;
  o.x = (pv.x - mean) * rs * gv.x + bv.x + xv.x;
  o.y = (pv.y - mean) * rs * gv.y + bv.y + xv.y;
  o.z = (pv.z - mean) * rs * gv.z + bv.z + xv.z;
  o.w = (pv.w - mean) * rs * gv.w + bv.w + xv.w;
  *reinterpret_cast<float4*>(out + base) = o;
}

extern "C" void kernel_launch(void* const* d_in, const int* in_sizes, int n_in,
                              void* d_out, int out_size, void* d_ws, size_t ws_size,
                              hipStream_t stream) {
  const float* x       = (const float*)d_in[0];
  const float* mark_W  = (const float*)d_in[1];
  const float* mark_b  = (const float*)d_in[2];
  const float* gate_W  = (const float*)d_in[3];
  const float* gate_b  = (const float*)d_in[4];
  const float* carry_g = (const float*)d_in[5];
  const float* carry_b = (const float*)d_in[6];
  const float* card_g  = (const float*)d_in[7];
  const float* card_b  = (const float*)d_in[8];
  const float* ho1_W   = (const float*)d_in[9];
  const float* ho1_b   = (const float*)d_in[10];
  const float* ho2_W   = (const float*)d_in[11];
  const float* ho2_b   = (const float*)d_in[12];
  const float* proj_W  = (const float*)d_in[13];
  const float* proj_b  = (const float*)d_in[14];
  const float* ln_g    = (const float*)d_in[15];
  const float* ln_b    = (const float*)d_in[16];
  float* out = (float*)d_out;

  char* ws = (char*)d_ws;
  // [0,33.5M): xbf ; [33.5M,67M): gm bf16 ; outpre fp32 aliases [0,67M) after both dead
  bf16_t* xbf    = (bf16_t*)(ws + 0);
  bf16_t* gm     = (bf16_t*)(ws + 33554432);
  float*  outpre = (float*)(ws + 0);
  bf16_t* cards  = (bf16_t*)(ws + 67108864);
  bf16_t* hobuf  = (bf16_t*)(ws + 100663296);
  float*  csum   = (float*)(ws + 134217728);
  float*  ncar   = (float*)(ws + 134742016);
  bf16_t* wtm    = (bf16_t*)(ws + 135266304);
  bf16_t* wtg    = (bf16_t*)(ws + 137363456);
  bf16_t* wtp    = (bf16_t*)(ws + 139460608);
  bf16_t* wt1    = (bf16_t*)(ws + 141557760);
  bf16_t* wt2    = (bf16_t*)(ws + 141590528);

  k_xbf<<<8192, 256, 0, stream>>>(x, xbf);
  k_transpose<<<dim3(16, 16), 256, 0, stream>>>(mark_W, wtm, 1024, 1024);
  k_transpose<<<dim3(16, 16), 256, 0, stream>>>(gate_W, wtg, 1024, 1024);
  k_transpose<<<dim3(16, 16), 256, 0, stream>>>(proj_W, wtp, 1024, 1024);
  k_transpose<<<dim3(2, 2),   256, 0, stream>>>(ho1_W, wt1, 128, 128);
  k_transpose<<<dim3(1, 2),   256, 0, stream>>>(ho2_W, wt2, 128, 64);

  k_dualgemm_gm<<<dim3(8, 128), 256, 0, stream>>>(xbf, wtm, wtg, mark_b, gate_b, gm);
  k_chunk_cumsum<<<512, 256, 0, stream>>>(gm, csum);
  k_carry_ln<<<64, 64, 0, stream>>>(csum, ncar, carry_g, carry_b);
  k_cards_ln<<<65536, 256, 0, stream>>>(gm, ncar, card_g, card_b, cards);
  k_ho_fused<<<2048, 256, 0, stream>>>(xbf, cards, wt1, ho1_b, wt2, ho2_b, hobuf);
  k_gemm_bt<<<dim3(8, 128), 256, 0, stream>>>(hobuf, wtp, proj_b, outpre);
  k_ln_residual<<<16384, 256, 0, stream>>>(outpre, x, ln_g, ln_b, out);
}

// Round 4
// 322.459 us; speedup vs baseline: 1.3474x; 1.0047x over previous
//
#include <hip/hip_runtime.h>
#include <hip/hip_bf16.h>

typedef __bf16 bf16_t;
typedef __attribute__((ext_vector_type(8))) __bf16 bf16x8;
typedef __attribute__((ext_vector_type(4))) __bf16 bf16x4;
typedef __attribute__((ext_vector_type(4))) float f32x4;

static constexpr int Bn = 4, Tn = 4096, Cn = 1024, Hn = 16, CSn = 128, Dn = 64, NCn = 32;

#define DEVINL __device__ __forceinline__

DEVINL float wsum64(float v) {
  v += __shfl_xor(v, 32, 64);
  v += __shfl_xor(v, 16, 64);
  v += __shfl_xor(v, 8, 64);
  v += __shfl_xor(v, 4, 64);
  v += __shfl_xor(v, 2, 64);
  v += __shfl_xor(v, 1, 64);
  return v;
}

// fast erf-based GELU (A&S 7.1.26, |erf err| <= 1.5e-7, far below bf16 rounding)
DEVINL float gelu_f(float v) {
  float x = v * 0.70710678f;
  float ax = fabsf(x);
  float t = 1.f / (1.f + 0.3275911f * ax);
  float poly = t * (0.254829592f +
               t * (-0.284496736f +
               t * (1.421413741f +
               t * (-1.453152027f +
               t * 1.061405429f))));
  float e = __expf(-ax * ax);
  float erfax = 1.f - poly * e;
  float erfx = copysignf(erfax, x);
  return 0.5f * v * (1.f + erfx);
}

// direct global->LDS, 16B per lane; LDS dest is wave-uniform base + lane*16
DEVINL void gld16(const bf16_t* g, bf16_t* l) {
  __builtin_amdgcn_global_load_lds(
      (const __attribute__((address_space(1))) unsigned int*)(g),
      (__attribute__((address_space(3))) unsigned int*)(l), 16, 0, 0);
}

// ------------- x fp32 -> bf16 (contiguous) -------------------------------------
__global__ __launch_bounds__(256) void k_xbf(const float* __restrict__ in,
                                             bf16_t* __restrict__ out) {
  int i = blockIdx.x * 256 + threadIdx.x;  // one per 8 elements
  float4 a = *reinterpret_cast<const float4*>(in + (size_t)i * 8);
  float4 b = *reinterpret_cast<const float4*>(in + (size_t)i * 8 + 4);
  bf16x8 o = {(bf16_t)a.x, (bf16_t)a.y, (bf16_t)a.z, (bf16_t)a.w,
              (bf16_t)b.x, (bf16_t)b.y, (bf16_t)b.z, (bf16_t)b.w};
  *reinterpret_cast<bf16x8*>(out + (size_t)i * 8) = o;
}

// ------------- transpose fp32 (rows x cols) -> bf16 (cols x rows) --------------
__global__ void k_transpose(const float* __restrict__ in, bf16_t* __restrict__ out,
                            int rows, int cols) {
  __shared__ float tile[64][65];
  int c0 = blockIdx.x * 64, r0 = blockIdx.y * 64;
  int tx = threadIdx.x & 63, ty = threadIdx.x >> 6;
#pragma unroll
  for (int i = ty; i < 64; i += 4)
    tile[i][tx] = in[(size_t)(r0 + i) * cols + c0 + tx];
  __syncthreads();
#pragma unroll
  for (int i = ty; i < 64; i += 4)
    out[(size_t)(c0 + i) * rows + r0 + tx] = (bf16_t)tile[tx][i];
}

// ---------------- fused dual GEMM: gm = sigmoid(x@gateW+bg) * (x@markW+bm) ------
// X: [BT x 1024] bf16. Wtm/Wtg: [1024 x 1024] bf16 = W^T (k-contig). gm: bf16.
__global__ __launch_bounds__(256, 2) void k_dualgemm_gm(
    const bf16_t* __restrict__ X, const bf16_t* __restrict__ Wtm,
    const bf16_t* __restrict__ Wtg, const float* __restrict__ bm,
    const float* __restrict__ bg, bf16_t* __restrict__ gm) {
  constexpr int K = Cn, N = Cn;
  __shared__ __align__(16) bf16_t As[128 * 64];
  __shared__ __align__(16) bf16_t Bms[128 * 64];
  __shared__ __align__(16) bf16_t Bgs[128 * 64];
  int tid = threadIdx.x;
  int m0 = blockIdx.y * 128, n0 = blockIdx.x * 128;
  int wave = tid >> 6, lane = tid & 63;
  int wm = wave >> 1, wn = wave & 1;
  int lr = lane & 15, lk = lane >> 4;
  int srow = lane >> 3, scol = (lane & 7) * 8;  // within 8-row chunk
  f32x4 accP[4][4] = {};
  f32x4 accG[4][4] = {};
  for (int kt = 0; kt < K / 64; ++kt) {
#pragma unroll
    for (int c2 = 0; c2 < 4; ++c2) {
      int chunk = wave * 4 + c2;       // 0..15
      int row = chunk * 8 + srow;      // 0..127
      size_t goff = (size_t)row * K + kt * 64 + scol;
      gld16(X + (size_t)m0 * K + goff, As + chunk * 512);
      gld16(Wtm + (size_t)n0 * K + goff, Bms + chunk * 512);
      gld16(Wtg + (size_t)n0 * K + goff, Bgs + chunk * 512);
    }
    __syncthreads();
#pragma unroll
    for (int ks = 0; ks < 2; ++ks) {
      bf16x8 af[4], bmf[4], bgf[4];
#pragma unroll
      for (int i = 0; i < 4; ++i)
        af[i] = *reinterpret_cast<const bf16x8*>(&As[(wm * 64 + i * 16 + lr) * 64 + ks * 32 + lk * 8]);
#pragma unroll
      for (int j = 0; j < 4; ++j) {
        bmf[j] = *reinterpret_cast<const bf16x8*>(&Bms[(wn * 64 + j * 16 + lr) * 64 + ks * 32 + lk * 8]);
        bgf[j] = *reinterpret_cast<const bf16x8*>(&Bgs[(wn * 64 + j * 16 + lr) * 64 + ks * 32 + lk * 8]);
      }
#pragma unroll
      for (int i = 0; i < 4; ++i)
#pragma unroll
        for (int j = 0; j < 4; ++j) {
          accP[i][j] = __builtin_amdgcn_mfma_f32_16x16x32_bf16(af[i], bmf[j], accP[i][j], 0, 0, 0);
          accG[i][j] = __builtin_amdgcn_mfma_f32_16x16x32_bf16(af[i], bgf[j], accG[i][j], 0, 0, 0);
        }
    }
    __syncthreads();
  }
#pragma unroll
  for (int j = 0; j < 4; ++j) {
    int col = n0 + wn * 64 + j * 16 + lr;
    float bmv = bm[col], bgv = bg[col];
#pragma unroll
    for (int i = 0; i < 4; ++i) {
      int rbase = m0 + wm * 64 + i * 16 + lk * 4;
#pragma unroll
      for (int r = 0; r < 4; ++r) {
        float p = accP[i][j][r] + bmv;
        float g = accG[i][j][r] + bgv;
        float s = 1.f / (1.f + __expf(-g));
        gm[(size_t)(rbase + r) * N + col] = (bf16_t)(s * p);
      }
    }
  }
}

// ---------------- per-(b,h,chunk) cumsum over pos (in-place, bf16) --------------
__global__ __launch_bounds__(256) void k_chunk_cumsum(bf16_t* __restrict__ gm,
                                                      float* __restrict__ csum) {
  int gid = blockIdx.x * 4 + (threadIdx.x >> 6);  // (b*H+h)*NC + ci
  int lane = threadIdx.x & 63;
  int ci = gid & 31, bh = gid >> 5;
  int h = bh & 15, b = bh >> 4;
  size_t base = ((size_t)(b * Tn + ci * CSn)) * Cn + h * Dn + lane;
  float run = 0.f;
#pragma unroll 8
  for (int pos = 0; pos < CSn; ++pos) {
    run += (float)gm[base + (size_t)pos * Cn];
    gm[base + (size_t)pos * Cn] = (bf16_t)run;
  }
  csum[(size_t)gid * 64 + lane] = run;
}

// ---------------- exclusive carry cumsum over chunks + LN(D) --------------------
__global__ __launch_bounds__(64) void k_carry_ln(const float* __restrict__ csum,
                                                 float* __restrict__ ncar,
                                                 const float* __restrict__ g,
                                                 const float* __restrict__ be) {
  int bh = blockIdx.x;
  int d = threadIdx.x;
  float gd = g[d], bd = be[d];
  float run = 0.f;
  for (int ci = 0; ci < NCn; ++ci) {
    float v = run;  // exclusive prefix
    run += csum[((size_t)bh * NCn + ci) * 64 + d];
    float m = wsum64(v) * (1.f / 64.f);
    float dv = v - m;
    float var = wsum64(dv * dv) * (1.f / 64.f);
    ncar[((size_t)bh * NCn + ci) * 64 + d] = dv * rsqrtf(var + 1e-5f) * gd + bd;
  }
}

// ---------------- cards = LN(shifted lcm + nrm_carry), bf16 out -----------------
__global__ __launch_bounds__(256) void k_cards_ln(const bf16_t* __restrict__ lcm,
                                                  const float* __restrict__ ncar,
                                                  const float* __restrict__ g,
                                                  const float* __restrict__ be,
                                                  bf16_t* __restrict__ cards) {
  int row = blockIdx.x * 4 + (threadIdx.x >> 6);  // ((bh*NC)+ci)*CS + pos
  int d = threadIdx.x & 63;
  int pos = row & 127, rem = row >> 7;
  int ci = rem & 31, bh = rem >> 5;
  int h = bh & 15, b = bh >> 4;
  float v = ncar[((size_t)bh * NCn + ci) * 64 + d];
  if (pos > 0)
    v += (float)lcm[((size_t)(b * Tn + ci * CSn + pos - 1)) * Cn + h * Dn + d];
  float m = wsum64(v) * (1.f / 64.f);
  float dv = v - m;
  float var = wsum64(dv * dv) * (1.f / 64.f);
  cards[(size_t)row * 64 + d] = (bf16_t)(dv * rsqrtf(var + 1e-5f) * g[d] + be[d]);
}

// ---------------- fused ho1 -> gelu -> ho2 per (b,h,chunk) ---------------------
// W1t: [128 x 128] bf16 = ho1_W^T ; W2t: [64 x 128] bf16 = ho2_W^T
// Weights read directly from global (L2-resident, shared by all 2048 blocks).
__global__ __launch_bounds__(256, 4) void k_ho_fused(
    const bf16_t* __restrict__ X, const bf16_t* __restrict__ cards,
    const bf16_t* __restrict__ W1t, const float* __restrict__ b1,
    const bf16_t* __restrict__ W2t, const float* __restrict__ b2,
    bf16_t* __restrict__ ho) {
  __shared__ __align__(16) bf16_t Cs[128][136];  // comb tile; reused as h tile
  int tid = threadIdx.x;
  int ci = blockIdx.x & 31, bh = blockIdx.x >> 5;
  int h = bh & 15, b = bh >> 4;
  int wave = tid >> 6, lane = tid & 63;
  int wm = wave >> 1, wn = wave & 1;
  int lr = lane & 15, lk = lane >> 4;
  size_t xrow0 = (size_t)(b * Tn + ci * CSn);
  // x half: 128 rows x 64 cols bf16
#pragma unroll
  for (int i = 0; i < 4; ++i) {
    int idx = tid + 256 * i;
    int row = idx >> 3, c8 = (idx & 7) * 8;
    *reinterpret_cast<uint4*>(&Cs[row][c8]) =
        *reinterpret_cast<const uint4*>(X + (xrow0 + row) * Cn + h * Dn + c8);
  }
  // cards half: 128 rows x 64 cols bf16 (contiguous source)
#pragma unroll
  for (int i = 0; i < 4; ++i) {
    int idx = tid + 256 * i;
    int row = idx >> 3, c8 = (idx & 7) * 8;
    *reinterpret_cast<uint4*>(&Cs[row][64 + c8]) =
        *reinterpret_cast<const uint4*>(cards + (((size_t)bh * NCn + ci) * CSn + row) * 64 + c8);
  }
  __syncthreads();
  f32x4 acc[4][4] = {};
#pragma unroll
  for (int ks = 0; ks < 4; ++ks) {
    bf16x8 af[4], bfr[4];
#pragma unroll
    for (int i = 0; i < 4; ++i)
      af[i] = *reinterpret_cast<const bf16x8*>(&Cs[wm * 64 + i * 16 + lr][ks * 32 + lk * 8]);
#pragma unroll
    for (int j = 0; j < 4; ++j)
      bfr[j] = *reinterpret_cast<const bf16x8*>(
          W1t + (size_t)(wn * 64 + j * 16 + lr) * 128 + ks * 32 + lk * 8);
#pragma unroll
    for (int i = 0; i < 4; ++i)
#pragma unroll
      for (int j = 0; j < 4; ++j)
        acc[i][j] = __builtin_amdgcn_mfma_f32_16x16x32_bf16(af[i], bfr[j], acc[i][j], 0, 0, 0);
  }
  __syncthreads();
  // h = gelu(acc + b1) into Cs
#pragma unroll
  for (int j = 0; j < 4; ++j) {
    int col = wn * 64 + j * 16 + lr;
    float bv = b1[col];
#pragma unroll
    for (int i = 0; i < 4; ++i) {
      int rbase = wm * 64 + i * 16 + lk * 4;
#pragma unroll
      for (int r = 0; r < 4; ++r)
        Cs[rbase + r][col] = (bf16_t)gelu_f(acc[i][j][r] + bv);
    }
  }
  __syncthreads();
  f32x4 acc2[2][4] = {};
#pragma unroll
  for (int ks = 0; ks < 4; ++ks) {
    bf16x8 af[2], bfr[4];
#pragma unroll
    for (int i = 0; i < 2; ++i)
      af[i] = *reinterpret_cast<const bf16x8*>(&Cs[wave * 32 + i * 16 + lr][ks * 32 + lk * 8]);
#pragma unroll
    for (int j = 0; j < 4; ++j)
      bfr[j] = *reinterpret_cast<const bf16x8*>(
          W2t + (size_t)(j * 16 + lr) * 128 + ks * 32 + lk * 8);
#pragma unroll
    for (int i = 0; i < 2; ++i)
#pragma unroll
      for (int j = 0; j < 4; ++j)
        acc2[i][j] = __builtin_amdgcn_mfma_f32_16x16x32_bf16(af[i], bfr[j], acc2[i][j], 0, 0, 0);
  }
#pragma unroll
  for (int j = 0; j < 4; ++j) {
    int dd = j * 16 + lr;
    float bv = b2[dd];
#pragma unroll
    for (int i = 0; i < 2; ++i) {
      int pbase = wave * 32 + i * 16 + lk * 4;
#pragma unroll
      for (int r = 0; r < 4; ++r)
        ho[(xrow0 + pbase + r) * Cn + h * Dn + dd] = (bf16_t)(acc2[i][j][r] + bv);
    }
  }
}

// ---------------- proj GEMM: out = A @ Wt^T + bias (fp32 out) ------------------
__global__ __launch_bounds__(256, 2) void k_gemm_bt(
    const bf16_t* __restrict__ A, const bf16_t* __restrict__ Wt,
    const float* __restrict__ bias, float* __restrict__ out) {
  constexpr int K = Cn, N = Cn;
  __shared__ __align__(16) bf16_t As[128 * 64];
  __shared__ __align__(16) bf16_t Bs[128 * 64];
  int tid = threadIdx.x;
  int m0 = blockIdx.y * 128, n0 = blockIdx.x * 128;
  int wave = tid >> 6, lane = tid & 63;
  int wm = wave >> 1, wn = wave & 1;
  int lr = lane & 15, lk = lane >> 4;
  int srow = lane >> 3, scol = (lane & 7) * 8;
  f32x4 acc[4][4] = {};
  for (int kt = 0; kt < K / 64; ++kt) {
#pragma unroll
    for (int c2 = 0; c2 < 4; ++c2) {
      int chunk = wave * 4 + c2;
      int row = chunk * 8 + srow;
      size_t goff = (size_t)row * K + kt * 64 + scol;
      gld16(A + (size_t)m0 * K + goff, As + chunk * 512);
      gld16(Wt + (size_t)n0 * K + goff, Bs + chunk * 512);
    }
    __syncthreads();
#pragma unroll
    for (int ks = 0; ks < 2; ++ks) {
      bf16x8 af[4], bfr[4];
#pragma unroll
      for (int i = 0; i < 4; ++i)
        af[i] = *reinterpret_cast<const bf16x8*>(&As[(wm * 64 + i * 16 + lr) * 64 + ks * 32 + lk * 8]);
#pragma unroll
      for (int j = 0; j < 4; ++j)
        bfr[j] = *reinterpret_cast<const bf16x8*>(&Bs[(wn * 64 + j * 16 + lr) * 64 + ks * 32 + lk * 8]);
#pragma unroll
      for (int i = 0; i < 4; ++i)
#pragma unroll
        for (int j = 0; j < 4; ++j)
          acc[i][j] = __builtin_amdgcn_mfma_f32_16x16x32_bf16(af[i], bfr[j], acc[i][j], 0, 0, 0);
    }
    __syncthreads();
  }
#pragma unroll
  for (int j = 0; j < 4; ++j) {
    int col = n0 + wn * 64 + j * 16 + lr;
    float bv = bias[col];
#pragma unroll
    for (int i = 0; i < 4; ++i) {
      int rbase = m0 + wm * 64 + i * 16 + lk * 4;
#pragma unroll
      for (int r = 0; r < 4; ++r)
        out[(size_t)(rbase + r) * N + col] = acc[i][j][r] + bv;
    }
  }
}

// ---------------- final LN over C + residual (all fp32) -------------------------
__global__ __launch_bounds__(256) void k_ln_residual(
    const float* __restrict__ pre, const float* __restrict__ X,
    const float* __restrict__ g, const float* __restrict__ be,
    float* __restrict__ out) {
  int row = blockIdx.x, t = threadIdx.x;
  size_t base = (size_t)row * Cn + t * 4;
  float4 pv = *reinterpret_cast<const float4*>(pre + base);
  float s = pv.x + pv.y + pv.z + pv.w;
  float q = pv.x * pv.x + pv.y * pv.y + pv.z * pv.z + pv.w * pv.w;
  s = wsum64(s);
  q = wsum64(q);
  __shared__ float red[8];
  int wv = t >> 6, ln = t & 63;
  if (ln == 0) { red[wv] = s; red[4 + wv] = q; }
  __syncthreads();
  float tot = red[0] + red[1] + red[2] + red[3];
  float totq = red[4] + red[5] + red[6] + red[7];
  float mean = tot * (1.f / 1024.f);
  float var = totq * (1.f / 1024.f) - mean * mean;
  float rs = rsqrtf(fmaxf(var, 0.f) + 1e-5f);
  float4 xv = *reinterpret_cast<const float4*>(X + base);
  float4 gv = *reinterpret_cast<const float4*>(g + t * 4);
  float4 bv = *reinterpret_cast<const float4*>(be + t * 4);
  float4 o;
  o.x = (pv.x - mean) * rs * gv.x + bv.x + xv.x;
  o.y = (pv.y - mean) * rs * gv.y + bv.y + xv.y;
  o.z = (pv.z - mean) * rs * gv.z + bv.z + xv.z;
  o.w = (pv.w - mean) * rs * gv.w + bv.w + xv.w;
  *reinterpret_cast<float4*>(out + base) = o;
}

extern "C" void kernel_launch(void* const* d_in, const int* in_sizes, int n_in,
                              void* d_out, int out_size, void* d_ws, size_t ws_size,
                              hipStream_t stream) {
  const float* x       = (const float*)d_in[0];
  const float* mark_W  = (const float*)d_in[1];
  const float* mark_b  = (const float*)d_in[2];
  const float* gate_W  = (const float*)d_in[3];
  const float* gate_b  = (const float*)d_in[4];
  const float* carry_g = (const float*)d_in[5];
  const float* carry_b = (const float*)d_in[6];
  const float* card_g  = (const float*)d_in[7];
  const float* card_b  = (const float*)d_in[8];
  const float* ho1_W   = (const float*)d_in[9];
  const float* ho1_b   = (const float*)d_in[10];
  const float* ho2_W   = (const float*)d_in[11];
  const float* ho2_b   = (const float*)d_in[12];
  const float* proj_W  = (const float*)d_in[13];
  const float* proj_b  = (const float*)d_in[14];
  const float* ln_g    = (const float*)d_in[15];
  const float* ln_b    = (const float*)d_in[16];
  float* out = (float*)d_out;

  char* ws = (char*)d_ws;
  // [0,33.5M): xbf ; [33.5M,67M): gm bf16 ; outpre fp32 aliases [0,67M) after both dead
  bf16_t* xbf    = (bf16_t*)(ws + 0);
  bf16_t* gm     = (bf16_t*)(ws + 33554432);
  float*  outpre = (float*)(ws + 0);
  bf16_t* cards  = (bf16_t*)(ws + 67108864);
  bf16_t* hobuf  = (bf16_t*)(ws + 100663296);
  float*  csum   = (float*)(ws + 134217728);
  float*  ncar   = (float*)(ws + 134742016);
  bf16_t* wtm    = (bf16_t*)(ws + 135266304);
  bf16_t* wtg    = (bf16_t*)(ws + 137363456);
  bf16_t* wtp    = (bf16_t*)(ws + 139460608);
  bf16_t* wt1    = (bf16_t*)(ws + 141557760);
  bf16_t* wt2    = (bf16_t*)(ws + 141590528);

  k_xbf<<<8192, 256, 0, stream>>>(x, xbf);
  k_transpose<<<dim3(16, 16), 256, 0, stream>>>(mark_W, wtm, 1024, 1024);
  k_transpose<<<dim3(16, 16), 256, 0, stream>>>(gate_W, wtg, 1024, 1024);
  k_transpose<<<dim3(16, 16), 256, 0, stream>>>(proj_W, wtp, 1024, 1024);
  k_transpose<<<dim3(2, 2),   256, 0, stream>>>(ho1_W, wt1, 128, 128);
  k_transpose<<<dim3(1, 2),   256, 0, stream>>>(ho2_W, wt2, 128, 64);

  k_dualgemm_gm<<<dim3(8, 128), 256, 0, stream>>>(xbf, wtm, wtg, mark_b, gate_b, gm);
  k_chunk_cumsum<<<512, 256, 0, stream>>>(gm, csum);
  k_carry_ln<<<64, 64, 0, stream>>>(csum, ncar, carry_g, carry_b);
  k_cards_ln<<<65536, 256, 0, stream>>>(gm, ncar, card_g, card_b, cards);
  k_ho_fused<<<2048, 256, 0, stream>>>(xbf, cards, wt1, ho1_b, wt2, ho2_b, hobuf);
  k_gemm_bt<<<dim3(8, 128), 256, 0, stream>>>(hobuf, wtp, proj_b, outpre);
  k_ln_residual<<<16384, 256, 0, stream>>>(outpre, x, ln_g, ln_b, out);
}

// Round 5
// 294.623 us; speedup vs baseline: 1.4747x; 1.0945x over previous
//
#include <hip/hip_runtime.h>
#include <hip/hip_bf16.h>

typedef __bf16 bf16_t;
typedef __attribute__((ext_vector_type(8))) __bf16 bf16x8;
typedef __attribute__((ext_vector_type(4))) __bf16 bf16x4;
typedef __attribute__((ext_vector_type(4))) float f32x4;

static constexpr int Bn = 4, Tn = 4096, Cn = 1024, Hn = 16, CSn = 128, Dn = 64, NCn = 32;

#define DEVINL __device__ __forceinline__

DEVINL float wsum64(float v) {
  v += __shfl_xor(v, 32, 64);
  v += __shfl_xor(v, 16, 64);
  v += __shfl_xor(v, 8, 64);
  v += __shfl_xor(v, 4, 64);
  v += __shfl_xor(v, 2, 64);
  v += __shfl_xor(v, 1, 64);
  return v;
}

// fast erf-based GELU (A&S 7.1.26, |erf err| <= 1.5e-7, far below bf16 rounding)
DEVINL float gelu_f(float v) {
  float x = v * 0.70710678f;
  float ax = fabsf(x);
  float t = 1.f / (1.f + 0.3275911f * ax);
  float poly = t * (0.254829592f +
               t * (-0.284496736f +
               t * (1.421413741f +
               t * (-1.453152027f +
               t * 1.061405429f))));
  float e = __expf(-ax * ax);
  float erfax = 1.f - poly * e;
  float erfx = copysignf(erfax, x);
  return 0.5f * v * (1.f + erfx);
}

// direct global->LDS, 16B per lane; LDS dest is wave-uniform base + lane*16
DEVINL void gld16(const bf16_t* g, bf16_t* l) {
  __builtin_amdgcn_global_load_lds(
      (const __attribute__((address_space(1))) unsigned int*)(g),
      (__attribute__((address_space(3))) unsigned int*)(l), 16, 0, 0);
}

// ------------- x fp32 -> bf16 (contiguous) -------------------------------------
__global__ __launch_bounds__(256) void k_xbf(const float* __restrict__ in,
                                             bf16_t* __restrict__ out) {
  int i = blockIdx.x * 256 + threadIdx.x;  // one per 8 elements
  float4 a = *reinterpret_cast<const float4*>(in + (size_t)i * 8);
  float4 b = *reinterpret_cast<const float4*>(in + (size_t)i * 8 + 4);
  bf16x8 o = {(bf16_t)a.x, (bf16_t)a.y, (bf16_t)a.z, (bf16_t)a.w,
              (bf16_t)b.x, (bf16_t)b.y, (bf16_t)b.z, (bf16_t)b.w};
  *reinterpret_cast<bf16x8*>(out + (size_t)i * 8) = o;
}

// ------------- transpose fp32 (rows x cols) -> bf16 (cols x rows) --------------
__global__ void k_transpose(const float* __restrict__ in, bf16_t* __restrict__ out,
                            int rows, int cols) {
  __shared__ float tile[64][65];
  int c0 = blockIdx.x * 64, r0 = blockIdx.y * 64;
  int tx = threadIdx.x & 63, ty = threadIdx.x >> 6;
#pragma unroll
  for (int i = ty; i < 64; i += 4)
    tile[i][tx] = in[(size_t)(r0 + i) * cols + c0 + tx];
  __syncthreads();
#pragma unroll
  for (int i = ty; i < 64; i += 4)
    out[(size_t)(c0 + i) * rows + r0 + tx] = (bf16_t)tile[tx][i];
}

// ---------------- fused dual GEMM + sigmoid*mul + chunk cumsum ------------------
// X: [BT x 1024] bf16. Wtm/Wtg: [1024 x 1024] bf16 = W^T (k-contig).
// Outputs: lcm (bf16, in-chunk cumsum of gm) and csum (fp32 chunk totals).
// Block = one (b,chunk) x 2 heads tile (128 rows x 128 cols). BK=32, dbuf, 2-phase.
__global__ __launch_bounds__(256, 2) void k_dualgemm_gm(
    const bf16_t* __restrict__ X, const bf16_t* __restrict__ Wtm,
    const bf16_t* __restrict__ Wtg, const float* __restrict__ bm,
    const float* __restrict__ bg, bf16_t* __restrict__ lcm,
    float* __restrict__ csum) {
  constexpr int K = Cn, N = Cn;
  __shared__ __align__(16) bf16_t L[6][128 * 32];  // A0 A1 Bm0 Bm1 Bg0 Bg1
  int tid = threadIdx.x;
  // bijective XCD swizzle: XCD k owns m == k (mod 8); its 8 n-blocks share X panel
  int Lb = blockIdx.x + 8 * blockIdx.y;  // 0..1023
  int xcd = Lb & 7, jj = Lb >> 3;
  int nb = jj & 7, mb = xcd + 8 * (jj >> 3);
  int m0 = mb * 128, n0 = nb * 128;
  int wave = tid >> 6, lane = tid & 63;
  int wm = wave >> 1, wn = wave & 1;
  int lr = lane & 15, lk = lane >> 4;
  int rl = lane >> 2;            // row within 16-row chunk
  int cl = (lane & 3) * 8;       // col elems within 32
  f32x4 accP[4][4] = {};
  f32x4 accG[4][4] = {};

  const bf16_t* Xb = X + (size_t)m0 * K;
  const bf16_t* Wmb = Wtm + (size_t)n0 * K;
  const bf16_t* Wgb = Wtg + (size_t)n0 * K;

#define STAGE3(buf, kt)                                                    \
  {                                                                        \
    _Pragma("unroll")                                                      \
    for (int c = 0; c < 2; ++c) {                                          \
      int ch = wave * 2 + c;                                               \
      size_t go = (size_t)(ch * 16 + rl) * K + (kt) * 32 + cl;             \
      int lo = ch * 512;                                                   \
      gld16(Xb + go, &L[0 + (buf)][lo]);                                   \
      gld16(Wmb + go, &L[2 + (buf)][lo]);                                  \
      gld16(Wgb + go, &L[4 + (buf)][lo]);                                  \
    }                                                                      \
  }

  STAGE3(0, 0);
  __syncthreads();
  int cur = 0;
  for (int kt = 0; kt < 32; ++kt) {
    if (kt < 31) STAGE3(cur ^ 1, kt + 1);
    bf16x8 af[4], bmf[4], bgf[4];
#pragma unroll
    for (int i = 0; i < 4; ++i)
      af[i] = *reinterpret_cast<const bf16x8*>(&L[0 + cur][(wm * 64 + i * 16 + lr) * 32 + lk * 8]);
#pragma unroll
    for (int j = 0; j < 4; ++j) {
      bmf[j] = *reinterpret_cast<const bf16x8*>(&L[2 + cur][(wn * 64 + j * 16 + lr) * 32 + lk * 8]);
      bgf[j] = *reinterpret_cast<const bf16x8*>(&L[4 + cur][(wn * 64 + j * 16 + lr) * 32 + lk * 8]);
    }
#pragma unroll
    for (int i = 0; i < 4; ++i)
#pragma unroll
      for (int j = 0; j < 4; ++j) {
        accP[i][j] = __builtin_amdgcn_mfma_f32_16x16x32_bf16(af[i], bmf[j], accP[i][j], 0, 0, 0);
        accG[i][j] = __builtin_amdgcn_mfma_f32_16x16x32_bf16(af[i], bgf[j], accG[i][j], 0, 0, 0);
      }
    __syncthreads();
    cur ^= 1;
  }
#undef STAGE3

  // epilogue: gm = sigmoid(G)*P -> LDS tile (bf16 [128][128], reuses L[0..3])
  bf16_t* G = &L[0][0];
#pragma unroll
  for (int j = 0; j < 4; ++j) {
    int col = wn * 64 + j * 16 + lr;
    float bmv = bm[n0 + col], bgv = bg[n0 + col];
#pragma unroll
    for (int i = 0; i < 4; ++i) {
      int rbase = wm * 64 + i * 16 + lk * 4;
#pragma unroll
      for (int r = 0; r < 4; ++r) {
        float p = accP[i][j][r] + bmv;
        float g = accG[i][j][r] + bgv;
        float s = 1.f / (1.f + __expf(-g));
        G[(rbase + r) * 128 + col] = (bf16_t)(s * p);
      }
    }
  }
  __syncthreads();
  // in-chunk cumsum over the 128 rows; block == one (b, chunk)
  if (tid < 128) {
    int col = tid;
    int bb = m0 >> 12;              // /4096
    int ci = (m0 & 4095) >> 7;      // /128
    int gc = n0 + col;              // global col = h*64 + d
    float run = 0.f;
    size_t obase = (size_t)m0 * N + gc;
#pragma unroll 8
    for (int pos = 0; pos < 128; ++pos) {
      run += (float)G[pos * 128 + col];
      lcm[obase + (size_t)pos * N] = (bf16_t)run;
    }
    csum[(((size_t)bb * Hn + (gc >> 6)) * NCn + ci) * 64 + (gc & 63)] = run;
  }
}

// ---------------- exclusive carry cumsum over chunks + LN(D) --------------------
__global__ __launch_bounds__(64) void k_carry_ln(const float* __restrict__ csum,
                                                 float* __restrict__ ncar,
                                                 const float* __restrict__ g,
                                                 const float* __restrict__ be) {
  int bh = blockIdx.x;
  int d = threadIdx.x;
  float gd = g[d], bd = be[d];
  float run = 0.f;
  for (int ci = 0; ci < NCn; ++ci) {
    float v = run;  // exclusive prefix
    run += csum[((size_t)bh * NCn + ci) * 64 + d];
    float m = wsum64(v) * (1.f / 64.f);
    float dv = v - m;
    float var = wsum64(dv * dv) * (1.f / 64.f);
    ncar[((size_t)bh * NCn + ci) * 64 + d] = dv * rsqrtf(var + 1e-5f) * gd + bd;
  }
}

// ---------------- cards = LN(shifted lcm + nrm_carry), bf16 out -----------------
__global__ __launch_bounds__(256) void k_cards_ln(const bf16_t* __restrict__ lcm,
                                                  const float* __restrict__ ncar,
                                                  const float* __restrict__ g,
                                                  const float* __restrict__ be,
                                                  bf16_t* __restrict__ cards) {
  int row = blockIdx.x * 4 + (threadIdx.x >> 6);  // ((bh*NC)+ci)*CS + pos
  int d = threadIdx.x & 63;
  int pos = row & 127, rem = row >> 7;
  int ci = rem & 31, bh = rem >> 5;
  int h = bh & 15, b = bh >> 4;
  float v = ncar[((size_t)bh * NCn + ci) * 64 + d];
  if (pos > 0)
    v += (float)lcm[((size_t)(b * Tn + ci * CSn + pos - 1)) * Cn + h * Dn + d];
  float m = wsum64(v) * (1.f / 64.f);
  float dv = v - m;
  float var = wsum64(dv * dv) * (1.f / 64.f);
  cards[(size_t)row * 64 + d] = (bf16_t)(dv * rsqrtf(var + 1e-5f) * g[d] + be[d]);
}

// ---------------- fused ho1 -> gelu -> ho2 per (b,h,chunk) ---------------------
// W1t: [128 x 128] bf16 = ho1_W^T ; W2t: [64 x 128] bf16 = ho2_W^T
// Weights read directly from global (L2-resident, shared by all 2048 blocks).
__global__ __launch_bounds__(256, 4) void k_ho_fused(
    const bf16_t* __restrict__ X, const bf16_t* __restrict__ cards,
    const bf16_t* __restrict__ W1t, const float* __restrict__ b1,
    const bf16_t* __restrict__ W2t, const float* __restrict__ b2,
    bf16_t* __restrict__ ho) {
  __shared__ __align__(16) bf16_t Cs[128][136];  // comb tile; reused as h tile
  int tid = threadIdx.x;
  int ci = blockIdx.x & 31, bh = blockIdx.x >> 5;
  int h = bh & 15, b = bh >> 4;
  int wave = tid >> 6, lane = tid & 63;
  int wm = wave >> 1, wn = wave & 1;
  int lr = lane & 15, lk = lane >> 4;
  size_t xrow0 = (size_t)(b * Tn + ci * CSn);
  // x half: 128 rows x 64 cols bf16
#pragma unroll
  for (int i = 0; i < 4; ++i) {
    int idx = tid + 256 * i;
    int row = idx >> 3, c8 = (idx & 7) * 8;
    *reinterpret_cast<uint4*>(&Cs[row][c8]) =
        *reinterpret_cast<const uint4*>(X + (xrow0 + row) * Cn + h * Dn + c8);
  }
  // cards half: 128 rows x 64 cols bf16 (contiguous source)
#pragma unroll
  for (int i = 0; i < 4; ++i) {
    int idx = tid + 256 * i;
    int row = idx >> 3, c8 = (idx & 7) * 8;
    *reinterpret_cast<uint4*>(&Cs[row][64 + c8]) =
        *reinterpret_cast<const uint4*>(cards + (((size_t)bh * NCn + ci) * CSn + row) * 64 + c8);
  }
  __syncthreads();
  f32x4 acc[4][4] = {};
#pragma unroll
  for (int ks = 0; ks < 4; ++ks) {
    bf16x8 af[4], bfr[4];
#pragma unroll
    for (int i = 0; i < 4; ++i)
      af[i] = *reinterpret_cast<const bf16x8*>(&Cs[wm * 64 + i * 16 + lr][ks * 32 + lk * 8]);
#pragma unroll
    for (int j = 0; j < 4; ++j)
      bfr[j] = *reinterpret_cast<const bf16x8*>(
          W1t + (size_t)(wn * 64 + j * 16 + lr) * 128 + ks * 32 + lk * 8);
#pragma unroll
    for (int i = 0; i < 4; ++i)
#pragma unroll
      for (int j = 0; j < 4; ++j)
        acc[i][j] = __builtin_amdgcn_mfma_f32_16x16x32_bf16(af[i], bfr[j], acc[i][j], 0, 0, 0);
  }
  __syncthreads();
  // h = gelu(acc + b1) into Cs
#pragma unroll
  for (int j = 0; j < 4; ++j) {
    int col = wn * 64 + j * 16 + lr;
    float bv = b1[col];
#pragma unroll
    for (int i = 0; i < 4; ++i) {
      int rbase = wm * 64 + i * 16 + lk * 4;
#pragma unroll
      for (int r = 0; r < 4; ++r)
        Cs[rbase + r][col] = (bf16_t)gelu_f(acc[i][j][r] + bv);
    }
  }
  __syncthreads();
  f32x4 acc2[2][4] = {};
#pragma unroll
  for (int ks = 0; ks < 4; ++ks) {
    bf16x8 af[2], bfr[4];
#pragma unroll
    for (int i = 0; i < 2; ++i)
      af[i] = *reinterpret_cast<const bf16x8*>(&Cs[wave * 32 + i * 16 + lr][ks * 32 + lk * 8]);
#pragma unroll
    for (int j = 0; j < 4; ++j)
      bfr[j] = *reinterpret_cast<const bf16x8*>(
          W2t + (size_t)(j * 16 + lr) * 128 + ks * 32 + lk * 8);
#pragma unroll
    for (int i = 0; i < 2; ++i)
#pragma unroll
      for (int j = 0; j < 4; ++j)
        acc2[i][j] = __builtin_amdgcn_mfma_f32_16x16x32_bf16(af[i], bfr[j], acc2[i][j], 0, 0, 0);
  }
#pragma unroll
  for (int j = 0; j < 4; ++j) {
    int dd = j * 16 + lr;
    float bv = b2[dd];
#pragma unroll
    for (int i = 0; i < 2; ++i) {
      int pbase = wave * 32 + i * 16 + lk * 4;
#pragma unroll
      for (int r = 0; r < 4; ++r)
        ho[(xrow0 + pbase + r) * Cn + h * Dn + dd] = (bf16_t)(acc2[i][j][r] + bv);
    }
  }
}

// ---------------- proj GEMM: out = A @ Wt^T + bias (bf16 out), 2-phase dbuf -----
__global__ __launch_bounds__(256, 2) void k_gemm_bt(
    const bf16_t* __restrict__ A, const bf16_t* __restrict__ Wt,
    const float* __restrict__ bias, bf16_t* __restrict__ out) {
  constexpr int K = Cn, N = Cn;
  __shared__ __align__(16) bf16_t L[4][128 * 32];  // A0 A1 B0 B1
  int tid = threadIdx.x;
  int Lb = blockIdx.x + 8 * blockIdx.y;
  int xcd = Lb & 7, jj = Lb >> 3;
  int nb = jj & 7, mb = xcd + 8 * (jj >> 3);
  int m0 = mb * 128, n0 = nb * 128;
  int wave = tid >> 6, lane = tid & 63;
  int wm = wave >> 1, wn = wave & 1;
  int lr = lane & 15, lk = lane >> 4;
  int rl = lane >> 2, cl = (lane & 3) * 8;
  f32x4 acc[4][4] = {};
  const bf16_t* Ab = A + (size_t)m0 * K;
  const bf16_t* Wb = Wt + (size_t)n0 * K;

#define STAGE2(buf, kt)                                                    \
  {                                                                        \
    _Pragma("unroll")                                                      \
    for (int c = 0; c < 2; ++c) {                                          \
      int ch = wave * 2 + c;                                               \
      size_t go = (size_t)(ch * 16 + rl) * K + (kt) * 32 + cl;             \
      int lo = ch * 512;                                                   \
      gld16(Ab + go, &L[0 + (buf)][lo]);                                   \
      gld16(Wb + go, &L[2 + (buf)][lo]);                                   \
    }                                                                      \
  }

  STAGE2(0, 0);
  __syncthreads();
  int cur = 0;
  for (int kt = 0; kt < 32; ++kt) {
    if (kt < 31) STAGE2(cur ^ 1, kt + 1);
    bf16x8 af[4], bfr[4];
#pragma unroll
    for (int i = 0; i < 4; ++i)
      af[i] = *reinterpret_cast<const bf16x8*>(&L[0 + cur][(wm * 64 + i * 16 + lr) * 32 + lk * 8]);
#pragma unroll
    for (int j = 0; j < 4; ++j)
      bfr[j] = *reinterpret_cast<const bf16x8*>(&L[2 + cur][(wn * 64 + j * 16 + lr) * 32 + lk * 8]);
#pragma unroll
    for (int i = 0; i < 4; ++i)
#pragma unroll
      for (int j = 0; j < 4; ++j)
        acc[i][j] = __builtin_amdgcn_mfma_f32_16x16x32_bf16(af[i], bfr[j], acc[i][j], 0, 0, 0);
    __syncthreads();
    cur ^= 1;
  }
#undef STAGE2
#pragma unroll
  for (int j = 0; j < 4; ++j) {
    int col = n0 + wn * 64 + j * 16 + lr;
    float bv = bias[col];
#pragma unroll
    for (int i = 0; i < 4; ++i) {
      int rbase = m0 + wm * 64 + i * 16 + lk * 4;
#pragma unroll
      for (int r = 0; r < 4; ++r)
        out[(size_t)(rbase + r) * N + col] = (bf16_t)(acc[i][j][r] + bv);
    }
  }
}

// ---------------- final LN over C + residual (bf16 pre, fp32 x/out) -------------
__global__ __launch_bounds__(256) void k_ln_residual(
    const bf16_t* __restrict__ pre, const float* __restrict__ X,
    const float* __restrict__ g, const float* __restrict__ be,
    float* __restrict__ out) {
  int row = blockIdx.x, t = threadIdx.x;
  size_t base = (size_t)row * Cn + t * 4;
  bf16x4 pv4 = *reinterpret_cast<const bf16x4*>(pre + base);
  float v0 = (float)pv4[0], v1 = (float)pv4[1], v2 = (float)pv4[2], v3 = (float)pv4[3];
  float s = v0 + v1 + v2 + v3;
  float q = v0 * v0 + v1 * v1 + v2 * v2 + v3 * v3;
  s = wsum64(s);
  q = wsum64(q);
  __shared__ float red[8];
  int wv = t >> 6, ln = t & 63;
  if (ln == 0) { red[wv] = s; red[4 + wv] = q; }
  __syncthreads();
  float tot = red[0] + red[1] + red[2] + red[3];
  float totq = red[4] + red[5] + red[6] + red[7];
  float mean = tot * (1.f / 1024.f);
  float var = totq * (1.f / 1024.f) - mean * mean;
  float rs = rsqrtf(fmaxf(var, 0.f) + 1e-5f);
  float4 xv = *reinterpret_cast<const float4*>(X + base);
  float4 gv = *reinterpret_cast<const float4*>(g + t * 4);
  float4 bv = *reinterpret_cast<const float4*>(be + t * 4);
  float4 o;
  o.x = (v0 - mean) * rs * gv.x + bv.x + xv.x;
  o.y = (v1 - mean) * rs * gv.y + bv.y + xv.y;
  o.z = (v2 - mean) * rs * gv.z + bv.z + xv.z;
  o.w = (v3 - mean) * rs * gv.w + bv.w + xv.w;
  *reinterpret_cast<float4*>(out + base) = o;
}

extern "C" void kernel_launch(void* const* d_in, const int* in_sizes, int n_in,
                              void* d_out, int out_size, void* d_ws, size_t ws_size,
                              hipStream_t stream) {
  const float* x       = (const float*)d_in[0];
  const float* mark_W  = (const float*)d_in[1];
  const float* mark_b  = (const float*)d_in[2];
  const float* gate_W  = (const float*)d_in[3];
  const float* gate_b  = (const float*)d_in[4];
  const float* carry_g = (const float*)d_in[5];
  const float* carry_b = (const float*)d_in[6];
  const float* card_g  = (const float*)d_in[7];
  const float* card_b  = (const float*)d_in[8];
  const float* ho1_W   = (const float*)d_in[9];
  const float* ho1_b   = (const float*)d_in[10];
  const float* ho2_W   = (const float*)d_in[11];
  const float* ho2_b   = (const float*)d_in[12];
  const float* proj_W  = (const float*)d_in[13];
  const float* proj_b  = (const float*)d_in[14];
  const float* ln_g    = (const float*)d_in[15];
  const float* ln_b    = (const float*)d_in[16];
  float* out = (float*)d_out;

  char* ws = (char*)d_ws;
  // [0,33.5M): xbf bf16, later reused for outpre bf16 (xbf dead after ho_fused)
  bf16_t* xbf    = (bf16_t*)(ws + 0);
  bf16_t* outpre = (bf16_t*)(ws + 0);
  bf16_t* gm     = (bf16_t*)(ws + 33554432);   // lcm (cumsum'd gm)
  bf16_t* cards  = (bf16_t*)(ws + 67108864);
  bf16_t* hobuf  = (bf16_t*)(ws + 100663296);
  float*  csum   = (float*)(ws + 134217728);
  float*  ncar   = (float*)(ws + 134742016);
  bf16_t* wtm    = (bf16_t*)(ws + 135266304);
  bf16_t* wtg    = (bf16_t*)(ws + 137363456);
  bf16_t* wtp    = (bf16_t*)(ws + 139460608);
  bf16_t* wt1    = (bf16_t*)(ws + 141557760);
  bf16_t* wt2    = (bf16_t*)(ws + 141590528);

  k_xbf<<<8192, 256, 0, stream>>>(x, xbf);
  k_transpose<<<dim3(16, 16), 256, 0, stream>>>(mark_W, wtm, 1024, 1024);
  k_transpose<<<dim3(16, 16), 256, 0, stream>>>(gate_W, wtg, 1024, 1024);
  k_transpose<<<dim3(16, 16), 256, 0, stream>>>(proj_W, wtp, 1024, 1024);
  k_transpose<<<dim3(2, 2),   256, 0, stream>>>(ho1_W, wt1, 128, 128);
  k_transpose<<<dim3(1, 2),   256, 0, stream>>>(ho2_W, wt2, 128, 64);

  k_dualgemm_gm<<<dim3(8, 128), 256, 0, stream>>>(xbf, wtm, wtg, mark_b, gate_b, gm, csum);
  k_carry_ln<<<64, 64, 0, stream>>>(csum, ncar, carry_g, carry_b);
  k_cards_ln<<<65536, 256, 0, stream>>>(gm, ncar, card_g, card_b, cards);
  k_ho_fused<<<2048, 256, 0, stream>>>(xbf, cards, wt1, ho1_b, wt2, ho2_b, hobuf);
  k_gemm_bt<<<dim3(8, 128), 256, 0, stream>>>(hobuf, wtp, proj_b, outpre);
  k_ln_residual<<<16384, 256, 0, stream>>>(outpre, x, ln_g, ln_b, out);
}

// Round 6
// 250.775 us; speedup vs baseline: 1.7326x; 1.1748x over previous
//
#include <hip/hip_runtime.h>
#include <hip/hip_bf16.h>

typedef __bf16 bf16_t;
typedef __attribute__((ext_vector_type(8))) __bf16 bf16x8;
typedef __attribute__((ext_vector_type(4))) __bf16 bf16x4;
typedef __attribute__((ext_vector_type(4))) float f32x4;

static constexpr int Bn = 4, Tn = 4096, Cn = 1024, Hn = 16, CSn = 128, Dn = 64, NCn = 32;

#define DEVINL __device__ __forceinline__

DEVINL float wsum64(float v) {
  v += __shfl_xor(v, 32, 64);
  v += __shfl_xor(v, 16, 64);
  v += __shfl_xor(v, 8, 64);
  v += __shfl_xor(v, 4, 64);
  v += __shfl_xor(v, 2, 64);
  v += __shfl_xor(v, 1, 64);
  return v;
}

// fast erf-based GELU (A&S 7.1.26, |erf err| <= 1.5e-7, far below bf16 rounding)
DEVINL float gelu_f(float v) {
  float x = v * 0.70710678f;
  float ax = fabsf(x);
  float t = 1.f / (1.f + 0.3275911f * ax);
  float poly = t * (0.254829592f +
               t * (-0.284496736f +
               t * (1.421413741f +
               t * (-1.453152027f +
               t * 1.061405429f))));
  float e = __expf(-ax * ax);
  float erfax = 1.f - poly * e;
  float erfx = copysignf(erfax, x);
  return 0.5f * v * (1.f + erfx);
}

// direct global->LDS, 16B per lane; LDS dest is wave-uniform base + lane*16
DEVINL void gld16(const bf16_t* g, bf16_t* l) {
  __builtin_amdgcn_global_load_lds(
      (const __attribute__((address_space(1))) unsigned int*)(g),
      (__attribute__((address_space(3))) unsigned int*)(l), 16, 0, 0);
}

// ------------- x fp32 -> bf16 (contiguous) -------------------------------------
__global__ __launch_bounds__(256) void k_xbf(const float* __restrict__ in,
                                             bf16_t* __restrict__ out) {
  int i = blockIdx.x * 256 + threadIdx.x;  // one per 8 elements
  float4 a = *reinterpret_cast<const float4*>(in + (size_t)i * 8);
  float4 b = *reinterpret_cast<const float4*>(in + (size_t)i * 8 + 4);
  bf16x8 o = {(bf16_t)a.x, (bf16_t)a.y, (bf16_t)a.z, (bf16_t)a.w,
              (bf16_t)b.x, (bf16_t)b.y, (bf16_t)b.z, (bf16_t)b.w};
  *reinterpret_cast<bf16x8*>(out + (size_t)i * 8) = o;
}

// ------------- transpose fp32 (rows x cols) -> bf16 (cols x rows) --------------
__global__ void k_transpose(const float* __restrict__ in, bf16_t* __restrict__ out,
                            int rows, int cols) {
  __shared__ float tile[64][65];
  int c0 = blockIdx.x * 64, r0 = blockIdx.y * 64;
  int tx = threadIdx.x & 63, ty = threadIdx.x >> 6;
#pragma unroll
  for (int i = ty; i < 64; i += 4)
    tile[i][tx] = in[(size_t)(r0 + i) * cols + c0 + tx];
  __syncthreads();
#pragma unroll
  for (int i = ty; i < 64; i += 4)
    out[(size_t)(c0 + i) * rows + r0 + tx] = (bf16_t)tile[tx][i];
}

// ---------------- fused dual GEMM + sigmoid*mul + chunk cumsum ------------------
// X: [BT x 1024] bf16. Wtm/Wtg: [1024 x 1024] bf16 = W^T (k-contig).
// Outputs: lcm (bf16, in-chunk cumsum of gm) and csum (fp32 chunk totals).
// Block = one (b,chunk) x 2 heads tile (128 rows x 128 cols). BK=32, dbuf, 2-phase.
__global__ __launch_bounds__(256, 2) void k_dualgemm_gm(
    const bf16_t* __restrict__ X, const bf16_t* __restrict__ Wtm,
    const bf16_t* __restrict__ Wtg, const float* __restrict__ bm,
    const float* __restrict__ bg, bf16_t* __restrict__ lcm,
    float* __restrict__ csum) {
  constexpr int K = Cn, N = Cn;
  constexpr int GP = 132;  // padded G-tile stride (conflict-free epilogue writes)
  __shared__ __align__(16) bf16_t L[6][128 * 32];  // A0 A1 Bm0 Bm1 Bg0 Bg1
  int tid = threadIdx.x;
  // bijective XCD swizzle: XCD k owns m == k (mod 8); its 8 n-blocks share X panel
  int Lb = blockIdx.x + 8 * blockIdx.y;  // 0..1023
  int xcd = Lb & 7, jj = Lb >> 3;
  int nb = jj & 7, mb = xcd + 8 * (jj >> 3);
  int m0 = mb * 128, n0 = nb * 128;
  int wave = tid >> 6, lane = tid & 63;
  int wm = wave >> 1, wn = wave & 1;
  int lr = lane & 15, lk = lane >> 4;
  int rl = lane >> 2;            // row within 16-row chunk
  int cl = (lane & 3) * 8;       // col elems within 32
  f32x4 accP[4][4] = {};
  f32x4 accG[4][4] = {};

  const bf16_t* Xb = X + (size_t)m0 * K;
  const bf16_t* Wmb = Wtm + (size_t)n0 * K;
  const bf16_t* Wgb = Wtg + (size_t)n0 * K;

#define STAGE3(buf, kt)                                                    \
  {                                                                        \
    _Pragma("unroll")                                                      \
    for (int c = 0; c < 2; ++c) {                                          \
      int ch = wave * 2 + c;                                               \
      size_t go = (size_t)(ch * 16 + rl) * K + (kt) * 32 + cl;             \
      int lo = ch * 512;                                                   \
      gld16(Xb + go, &L[0 + (buf)][lo]);                                   \
      gld16(Wmb + go, &L[2 + (buf)][lo]);                                  \
      gld16(Wgb + go, &L[4 + (buf)][lo]);                                  \
    }                                                                      \
  }

  STAGE3(0, 0);
  __syncthreads();
  int cur = 0;
  for (int kt = 0; kt < 32; ++kt) {
    if (kt < 31) STAGE3(cur ^ 1, kt + 1);
    bf16x8 af[4], bmf[4], bgf[4];
#pragma unroll
    for (int i = 0; i < 4; ++i)
      af[i] = *reinterpret_cast<const bf16x8*>(&L[0 + cur][(wm * 64 + i * 16 + lr) * 32 + lk * 8]);
#pragma unroll
    for (int j = 0; j < 4; ++j) {
      bmf[j] = *reinterpret_cast<const bf16x8*>(&L[2 + cur][(wn * 64 + j * 16 + lr) * 32 + lk * 8]);
      bgf[j] = *reinterpret_cast<const bf16x8*>(&L[4 + cur][(wn * 64 + j * 16 + lr) * 32 + lk * 8]);
    }
#pragma unroll
    for (int i = 0; i < 4; ++i)
#pragma unroll
      for (int j = 0; j < 4; ++j) {
        accP[i][j] = __builtin_amdgcn_mfma_f32_16x16x32_bf16(af[i], bmf[j], accP[i][j], 0, 0, 0);
        accG[i][j] = __builtin_amdgcn_mfma_f32_16x16x32_bf16(af[i], bgf[j], accG[i][j], 0, 0, 0);
      }
    __syncthreads();
    cur ^= 1;
  }
#undef STAGE3

  // epilogue: gm = sigmoid(G)*P -> LDS tile (bf16 [128][GP], reuses L)
  bf16_t* G = &L[0][0];
#pragma unroll
  for (int j = 0; j < 4; ++j) {
    int col = wn * 64 + j * 16 + lr;
    float bmv = bm[n0 + col], bgv = bg[n0 + col];
#pragma unroll
    for (int i = 0; i < 4; ++i) {
      int rbase = wm * 64 + i * 16 + lk * 4;
#pragma unroll
      for (int r = 0; r < 4; ++r) {
        float p = accP[i][j][r] + bmv;
        float g = accG[i][j][r] + bgv;
        float s = 1.f / (1.f + __expf(-g));
        G[(rbase + r) * GP + col] = (bf16_t)(s * p);
      }
    }
  }
  __syncthreads();
  // in-chunk cumsum over the 128 rows; block == one (b, chunk)
  if (tid < 128) {
    int col = tid;
    int bb = m0 >> 12;              // /4096
    int ci = (m0 & 4095) >> 7;      // /128
    int gc = n0 + col;              // global col = h*64 + d
    float run = 0.f;
    size_t obase = (size_t)m0 * N + gc;
#pragma unroll 8
    for (int pos = 0; pos < 128; ++pos) {
      run += (float)G[pos * GP + col];
      lcm[obase + (size_t)pos * N] = (bf16_t)run;
    }
    csum[(((size_t)bb * Hn + (gc >> 6)) * NCn + ci) * 64 + (gc & 63)] = run;
  }
}

// ---------------- exclusive carry cumsum over chunks + LN(D) --------------------
__global__ __launch_bounds__(64) void k_carry_ln(const float* __restrict__ csum,
                                                 float* __restrict__ ncar,
                                                 const float* __restrict__ g,
                                                 const float* __restrict__ be) {
  int bh = blockIdx.x;
  int d = threadIdx.x;
  float gd = g[d], bd = be[d];
  float run = 0.f;
  for (int ci = 0; ci < NCn; ++ci) {
    float v = run;  // exclusive prefix
    run += csum[((size_t)bh * NCn + ci) * 64 + d];
    float m = wsum64(v) * (1.f / 64.f);
    float dv = v - m;
    float var = wsum64(dv * dv) * (1.f / 64.f);
    ncar[((size_t)bh * NCn + ci) * 64 + d] = dv * rsqrtf(var + 1e-5f) * gd + bd;
  }
}

// ---------------- fused cards-LN + ho1 -> gelu -> ho2 per (b,h,chunk) -----------
// cards computed in-kernel: cards[p] = LN(ncar + (p>0 ? lcm[p-1] : 0)).
// W1t: [128 x 128] bf16 = ho1_W^T ; W2t: [64 x 128] bf16 = ho2_W^T (L2-resident).
__global__ __launch_bounds__(256, 4) void k_ho_fused(
    const bf16_t* __restrict__ X, const bf16_t* __restrict__ lcm,
    const float* __restrict__ ncar, const float* __restrict__ cg,
    const float* __restrict__ cb, const bf16_t* __restrict__ W1t,
    const float* __restrict__ b1, const bf16_t* __restrict__ W2t,
    const float* __restrict__ b2, bf16_t* __restrict__ ho) {
  __shared__ __align__(16) bf16_t Cs[128][136];  // comb tile; reused as h tile
  int tid = threadIdx.x;
  int ci = blockIdx.x & 31, bh = blockIdx.x >> 5;
  int h = bh & 15, b = bh >> 4;
  int wave = tid >> 6, lane = tid & 63;
  int wm = wave >> 1, wn = wave & 1;
  int lr = lane & 15, lk = lane >> 4;
  size_t xrow0 = (size_t)(b * Tn + ci * CSn);
  // x half: 128 rows x 64 cols bf16
#pragma unroll
  for (int i = 0; i < 4; ++i) {
    int idx = tid + 256 * i;
    int row = idx >> 3, c8 = (idx & 7) * 8;
    *reinterpret_cast<uint4*>(&Cs[row][c8]) =
        *reinterpret_cast<const uint4*>(X + (xrow0 + row) * Cn + h * Dn + c8);
  }
  // cards half: in-register LN. 8 groups of 8 lanes; group handles one row at a time.
  {
    int lg = lane >> 3;   // row offset within an 8-row batch
    int le = lane & 7;    // which 8-elem slice of d
    int d0 = le * 8;
    const float* np = ncar + ((size_t)bh * NCn + ci) * 64 + d0;
    float ncv[8], ggv[8], bbv[8];
#pragma unroll
    for (int e = 0; e < 8; ++e) {
      ncv[e] = np[e];
      ggv[e] = cg[d0 + e];
      bbv[e] = cb[d0 + e];
    }
#pragma unroll
    for (int it = 0; it < 4; ++it) {
      int pr = wave * 32 + it * 8 + lg;   // 0..127
      float v[8];
      if (pr > 0) {
        bf16x8 lv = *reinterpret_cast<const bf16x8*>(
            lcm + (xrow0 + pr - 1) * Cn + h * Dn + d0);
#pragma unroll
        for (int e = 0; e < 8; ++e) v[e] = (float)lv[e] + ncv[e];
      } else {
#pragma unroll
        for (int e = 0; e < 8; ++e) v[e] = ncv[e];
      }
      float s = 0.f, q = 0.f;
#pragma unroll
      for (int e = 0; e < 8; ++e) { s += v[e]; q += v[e] * v[e]; }
      s += __shfl_xor(s, 1, 64); q += __shfl_xor(q, 1, 64);
      s += __shfl_xor(s, 2, 64); q += __shfl_xor(q, 2, 64);
      s += __shfl_xor(s, 4, 64); q += __shfl_xor(q, 4, 64);
      float mean = s * (1.f / 64.f);
      float var = q * (1.f / 64.f) - mean * mean;
      float rs = rsqrtf(fmaxf(var, 0.f) + 1e-5f);
      bf16x8 o;
#pragma unroll
      for (int e = 0; e < 8; ++e)
        o[e] = (bf16_t)((v[e] - mean) * rs * ggv[e] + bbv[e]);
      *reinterpret_cast<bf16x8*>(&Cs[pr][64 + d0]) = o;
    }
  }
  __syncthreads();
  f32x4 acc[4][4] = {};
#pragma unroll
  for (int ks = 0; ks < 4; ++ks) {
    bf16x8 af[4], bfr[4];
#pragma unroll
    for (int i = 0; i < 4; ++i)
      af[i] = *reinterpret_cast<const bf16x8*>(&Cs[wm * 64 + i * 16 + lr][ks * 32 + lk * 8]);
#pragma unroll
    for (int j = 0; j < 4; ++j)
      bfr[j] = *reinterpret_cast<const bf16x8*>(
          W1t + (size_t)(wn * 64 + j * 16 + lr) * 128 + ks * 32 + lk * 8);
#pragma unroll
    for (int i = 0; i < 4; ++i)
#pragma unroll
      for (int j = 0; j < 4; ++j)
        acc[i][j] = __builtin_amdgcn_mfma_f32_16x16x32_bf16(af[i], bfr[j], acc[i][j], 0, 0, 0);
  }
  __syncthreads();
  // h = gelu(acc + b1) into Cs
#pragma unroll
  for (int j = 0; j < 4; ++j) {
    int col = wn * 64 + j * 16 + lr;
    float bv = b1[col];
#pragma unroll
    for (int i = 0; i < 4; ++i) {
      int rbase = wm * 64 + i * 16 + lk * 4;
#pragma unroll
      for (int r = 0; r < 4; ++r)
        Cs[rbase + r][col] = (bf16_t)gelu_f(acc[i][j][r] + bv);
    }
  }
  __syncthreads();
  f32x4 acc2[2][4] = {};
#pragma unroll
  for (int ks = 0; ks < 4; ++ks) {
    bf16x8 af[2], bfr[4];
#pragma unroll
    for (int i = 0; i < 2; ++i)
      af[i] = *reinterpret_cast<const bf16x8*>(&Cs[wave * 32 + i * 16 + lr][ks * 32 + lk * 8]);
#pragma unroll
    for (int j = 0; j < 4; ++j)
      bfr[j] = *reinterpret_cast<const bf16x8*>(
          W2t + (size_t)(j * 16 + lr) * 128 + ks * 32 + lk * 8);
#pragma unroll
    for (int i = 0; i < 2; ++i)
#pragma unroll
      for (int j = 0; j < 4; ++j)
        acc2[i][j] = __builtin_amdgcn_mfma_f32_16x16x32_bf16(af[i], bfr[j], acc2[i][j], 0, 0, 0);
  }
#pragma unroll
  for (int j = 0; j < 4; ++j) {
    int dd = j * 16 + lr;
    float bv = b2[dd];
#pragma unroll
    for (int i = 0; i < 2; ++i) {
      int pbase = wave * 32 + i * 16 + lk * 4;
#pragma unroll
      for (int r = 0; r < 4; ++r)
        ho[(xrow0 + pbase + r) * Cn + h * Dn + dd] = (bf16_t)(acc2[i][j][r] + bv);
    }
  }
}

// ---------------- proj GEMM: out = A @ Wt^T + bias (bf16 out), 2-phase dbuf -----
__global__ __launch_bounds__(256, 2) void k_gemm_bt(
    const bf16_t* __restrict__ A, const bf16_t* __restrict__ Wt,
    const float* __restrict__ bias, bf16_t* __restrict__ out) {
  constexpr int K = Cn, N = Cn;
  __shared__ __align__(16) bf16_t L[4][128 * 32];  // A0 A1 B0 B1
  int tid = threadIdx.x;
  int Lb = blockIdx.x + 8 * blockIdx.y;
  int xcd = Lb & 7, jj = Lb >> 3;
  int nb = jj & 7, mb = xcd + 8 * (jj >> 3);
  int m0 = mb * 128, n0 = nb * 128;
  int wave = tid >> 6, lane = tid & 63;
  int wm = wave >> 1, wn = wave & 1;
  int lr = lane & 15, lk = lane >> 4;
  int rl = lane >> 2, cl = (lane & 3) * 8;
  f32x4 acc[4][4] = {};
  const bf16_t* Ab = A + (size_t)m0 * K;
  const bf16_t* Wb = Wt + (size_t)n0 * K;

#define STAGE2(buf, kt)                                                    \
  {                                                                        \
    _Pragma("unroll")                                                      \
    for (int c = 0; c < 2; ++c) {                                          \
      int ch = wave * 2 + c;                                               \
      size_t go = (size_t)(ch * 16 + rl) * K + (kt) * 32 + cl;             \
      int lo = ch * 512;                                                   \
      gld16(Ab + go, &L[0 + (buf)][lo]);                                   \
      gld16(Wb + go, &L[2 + (buf)][lo]);                                   \
    }                                                                      \
  }

  STAGE2(0, 0);
  __syncthreads();
  int cur = 0;
  for (int kt = 0; kt < 32; ++kt) {
    if (kt < 31) STAGE2(cur ^ 1, kt + 1);
    bf16x8 af[4], bfr[4];
#pragma unroll
    for (int i = 0; i < 4; ++i)
      af[i] = *reinterpret_cast<const bf16x8*>(&L[0 + cur][(wm * 64 + i * 16 + lr) * 32 + lk * 8]);
#pragma unroll
    for (int j = 0; j < 4; ++j)
      bfr[j] = *reinterpret_cast<const bf16x8*>(&L[2 + cur][(wn * 64 + j * 16 + lr) * 32 + lk * 8]);
#pragma unroll
    for (int i = 0; i < 4; ++i)
#pragma unroll
      for (int j = 0; j < 4; ++j)
        acc[i][j] = __builtin_amdgcn_mfma_f32_16x16x32_bf16(af[i], bfr[j], acc[i][j], 0, 0, 0);
    __syncthreads();
    cur ^= 1;
  }
#undef STAGE2
#pragma unroll
  for (int j = 0; j < 4; ++j) {
    int col = n0 + wn * 64 + j * 16 + lr;
    float bv = bias[col];
#pragma unroll
    for (int i = 0; i < 4; ++i) {
      int rbase = m0 + wm * 64 + i * 16 + lk * 4;
#pragma unroll
      for (int r = 0; r < 4; ++r)
        out[(size_t)(rbase + r) * N + col] = (bf16_t)(acc[i][j][r] + bv);
    }
  }
}

// ---------------- final LN over C + residual (bf16 pre, fp32 x/out) -------------
__global__ __launch_bounds__(256) void k_ln_residual(
    const bf16_t* __restrict__ pre, const float* __restrict__ X,
    const float* __restrict__ g, const float* __restrict__ be,
    float* __restrict__ out) {
  int row = blockIdx.x, t = threadIdx.x;
  size_t base = (size_t)row * Cn + t * 4;
  bf16x4 pv4 = *reinterpret_cast<const bf16x4*>(pre + base);
  float v0 = (float)pv4[0], v1 = (float)pv4[1], v2 = (float)pv4[2], v3 = (float)pv4[3];
  float s = v0 + v1 + v2 + v3;
  float q = v0 * v0 + v1 * v1 + v2 * v2 + v3 * v3;
  s = wsum64(s);
  q = wsum64(q);
  __shared__ float red[8];
  int wv = t >> 6, ln = t & 63;
  if (ln == 0) { red[wv] = s; red[4 + wv] = q; }
  __syncthreads();
  float tot = red[0] + red[1] + red[2] + red[3];
  float totq = red[4] + red[5] + red[6] + red[7];
  float mean = tot * (1.f / 1024.f);
  float var = totq * (1.f / 1024.f) - mean * mean;
  float rs = rsqrtf(fmaxf(var, 0.f) + 1e-5f);
  float4 xv = *reinterpret_cast<const float4*>(X + base);
  float4 gv = *reinterpret_cast<const float4*>(g + t * 4);
  float4 bv = *reinterpret_cast<const float4*>(be + t * 4);
  float4 o;
  o.x = (v0 - mean) * rs * gv.x + bv.x + xv.x;
  o.y = (v1 - mean) * rs * gv.y + bv.y + xv.y;
  o.z = (v2 - mean) * rs * gv.z + bv.z + xv.z;
  o.w = (v3 - mean) * rs * gv.w + bv.w + xv.w;
  *reinterpret_cast<float4*>(out + base) = o;
}

extern "C" void kernel_launch(void* const* d_in, const int* in_sizes, int n_in,
                              void* d_out, int out_size, void* d_ws, size_t ws_size,
                              hipStream_t stream) {
  const float* x       = (const float*)d_in[0];
  const float* mark_W  = (const float*)d_in[1];
  const float* mark_b  = (const float*)d_in[2];
  const float* gate_W  = (const float*)d_in[3];
  const float* gate_b  = (const float*)d_in[4];
  const float* carry_g = (const float*)d_in[5];
  const float* carry_b = (const float*)d_in[6];
  const float* card_g  = (const float*)d_in[7];
  const float* card_b  = (const float*)d_in[8];
  const float* ho1_W   = (const float*)d_in[9];
  const float* ho1_b   = (const float*)d_in[10];
  const float* ho2_W   = (const float*)d_in[11];
  const float* ho2_b   = (const float*)d_in[12];
  const float* proj_W  = (const float*)d_in[13];
  const float* proj_b  = (const float*)d_in[14];
  const float* ln_g    = (const float*)d_in[15];
  const float* ln_b    = (const float*)d_in[16];
  float* out = (float*)d_out;

  char* ws = (char*)d_ws;
  // [0,33.5M): xbf bf16, later reused for outpre bf16 (xbf dead after ho_fused)
  bf16_t* xbf    = (bf16_t*)(ws + 0);
  bf16_t* outpre = (bf16_t*)(ws + 0);
  bf16_t* gm     = (bf16_t*)(ws + 33554432);   // lcm (cumsum'd gm)
  bf16_t* hobuf  = (bf16_t*)(ws + 100663296);
  float*  csum   = (float*)(ws + 134217728);
  float*  ncar   = (float*)(ws + 134742016);
  bf16_t* wtm    = (bf16_t*)(ws + 135266304);
  bf16_t* wtg    = (bf16_t*)(ws + 137363456);
  bf16_t* wtp    = (bf16_t*)(ws + 139460608);
  bf16_t* wt1    = (bf16_t*)(ws + 141557760);
  bf16_t* wt2    = (bf16_t*)(ws + 141590528);

  k_xbf<<<8192, 256, 0, stream>>>(x, xbf);
  k_transpose<<<dim3(16, 16), 256, 0, stream>>>(mark_W, wtm, 1024, 1024);
  k_transpose<<<dim3(16, 16), 256, 0, stream>>>(gate_W, wtg, 1024, 1024);
  k_transpose<<<dim3(16, 16), 256, 0, stream>>>(proj_W, wtp, 1024, 1024);
  k_transpose<<<dim3(2, 2),   256, 0, stream>>>(ho1_W, wt1, 128, 128);
  k_transpose<<<dim3(1, 2),   256, 0, stream>>>(ho2_W, wt2, 128, 64);

  k_dualgemm_gm<<<dim3(8, 128), 256, 0, stream>>>(xbf, wtm, wtg, mark_b, gate_b, gm, csum);
  k_carry_ln<<<64, 64, 0, stream>>>(csum, ncar, carry_g, carry_b);
  k_ho_fused<<<2048, 256, 0, stream>>>(xbf, gm, ncar, card_g, card_b,
                                       wt1, ho1_b, wt2, ho2_b, hobuf);
  k_gemm_bt<<<dim3(8, 128), 256, 0, stream>>>(hobuf, wtp, proj_b, outpre);
  k_ln_residual<<<16384, 256, 0, stream>>>(outpre, x, ln_g, ln_b, out);
}